// Round 10
// baseline (353.484 us; speedup 1.0000x reference)
//
#include <hip/hip_runtime.h>
#include <math.h>

#define N_NODES 100000
#define N_EDGES 600000
#define DIM 128
#define LN_EPS 1e-5f
#define SCAN_NBLK ((N_NODES + 255) / 256)  // 391
#define NTILES ((N_NODES + 127) / 128)     // 782
#define MG_GRID 512

typedef __bf16 bf16x8 __attribute__((ext_vector_type(8)));
typedef __bf16 bf16x4 __attribute__((ext_vector_type(4)));
typedef float f32x4 __attribute__((ext_vector_type(4)));

// ---------------- prep: h f32 -> bf16 (8 elems/thread), fused degree count ----------------
__global__ __launch_bounds__(256)
void prep_kernel(const float* __restrict__ h, const int* __restrict__ edst,
                 __bf16* __restrict__ h_bf, int* __restrict__ counts) {
  int i = blockIdx.x * 256 + threadIdx.x;  // 1,600,000 threads exactly
  {
    const float4 v0 = *reinterpret_cast<const float4*>(h + (size_t)i * 8);
    const float4 v1 = *reinterpret_cast<const float4*>(h + (size_t)i * 8 + 4);
    bf16x8 b;
    b[0] = (__bf16)v0.x; b[1] = (__bf16)v0.y; b[2] = (__bf16)v0.z; b[3] = (__bf16)v0.w;
    b[4] = (__bf16)v1.x; b[5] = (__bf16)v1.y; b[6] = (__bf16)v1.z; b[7] = (__bf16)v1.w;
    *reinterpret_cast<bf16x8*>(h_bf + (size_t)i * 8) = b;
  }
  if (i < N_EDGES) atomicAdd(&counts[edst[i]], 1);
}

// ---------------- CSR build ----------------
__global__ __launch_bounds__(256)
void scan1_kernel(const int* __restrict__ counts, int* __restrict__ block_sums) {
  int i = blockIdx.x * 256 + threadIdx.x;
  int v = (i < N_NODES) ? counts[i] : 0;
#pragma unroll
  for (int off = 1; off < 64; off <<= 1) v += __shfl_xor(v, off);
  __shared__ int ws[4];
  if ((threadIdx.x & 63) == 0) ws[threadIdx.x >> 6] = v;
  __syncthreads();
  if (threadIdx.x == 0) block_sums[blockIdx.x] = ws[0] + ws[1] + ws[2] + ws[3];
}

__global__ __launch_bounds__(256)
void scan3_kernel(const int* __restrict__ counts, const int* __restrict__ block_sums,
                  int* __restrict__ row_off, int* __restrict__ cursor) {
  const int i = blockIdx.x * 256 + threadIdx.x;
  const int t = threadIdx.x;
  const int lane = t & 63, wv = t >> 6;
  __shared__ int wtot[4];
  __shared__ int sbase[4];

  int partial = 0;
  for (int j = t; j < blockIdx.x; j += 256) partial += block_sums[j];
#pragma unroll
  for (int off = 1; off < 64; off <<= 1) partial += __shfl_xor(partial, off);
  if (lane == 0) sbase[wv] = partial;
  __syncthreads();
  const int base = sbase[0] + sbase[1] + sbase[2] + sbase[3];

  int v = (i < N_NODES) ? counts[i] : 0;
  int s = v;
#pragma unroll
  for (int off = 1; off < 64; off <<= 1) {
    int u = __shfl_up(s, off);
    if (lane >= off) s += u;
  }
  if (lane == 63) wtot[wv] = s;
  __syncthreads();
  int wo = 0;
  for (int w = 0; w < wv; ++w) wo += wtot[w];
  int excl = base + wo + (s - v);
  if (i < N_NODES) { row_off[i] = excl; cursor[i] = 0; }
  if (i == 0) row_off[N_NODES] = N_EDGES;
}

__global__ __launch_bounds__(256)
void csr_fill_kernel(const int* __restrict__ esrc, const int* __restrict__ edst,
                     const int* __restrict__ row_off, int* __restrict__ cursor,
                     int* __restrict__ csr_src) {
  int base = (blockIdx.x * 256 + threadIdx.x) * 4;
  if (base >= N_EDGES) return;
  int4 s4 = *reinterpret_cast<const int4*>(esrc + base);
  int4 d4 = *reinterpret_cast<const int4*>(edst + base);
  {
    int pos = atomicAdd(&cursor[d4.x], 1);
    csr_src[row_off[d4.x] + pos] = s4.x;
  }
  {
    int pos = atomicAdd(&cursor[d4.y], 1);
    csr_src[row_off[d4.y] + pos] = s4.y;
  }
  {
    int pos = atomicAdd(&cursor[d4.z], 1);
    csr_src[row_off[d4.z] + pos] = s4.z;
  }
  {
    int pos = atomicAdd(&cursor[d4.w], 1);
    csr_src[row_off[d4.w] + pos] = s4.w;
  }
}

// ---------------- gather mean: 16 lanes x 16B per node, batch-8 rows in flight ----------------
__global__ __launch_bounds__(256)
void gather_kernel(const __bf16* __restrict__ h_bf, const int* __restrict__ csr_src,
                   const int* __restrict__ row_off, __bf16* __restrict__ mean_bf) {
  int node = blockIdx.x * 16 + (threadIdx.x >> 4);
  if (node >= N_NODES) return;
  int t = threadIdx.x & 15;
  int b = row_off[node], e = row_off[node + 1];
  float acc[8];
#pragma unroll
  for (int j = 0; j < 8; ++j) acc[j] = 0.f;
  for (int i = b; i < e; i += 8) {
    int idx[8];
#pragma unroll
    for (int j = 0; j < 8; ++j) idx[j] = (i + j < e) ? csr_src[i + j] : -1;
    bf16x8 v[8];
#pragma unroll
    for (int j = 0; j < 8; ++j) {
      if (idx[j] >= 0)
        v[j] = *reinterpret_cast<const bf16x8*>(h_bf + (size_t)idx[j] * DIM + t * 8);
      else
#pragma unroll
        for (int k = 0; k < 8; ++k) v[j][k] = (__bf16)0.f;
    }
#pragma unroll
    for (int j = 0; j < 8; ++j)
#pragma unroll
      for (int k = 0; k < 8; ++k) acc[k] += (float)v[j][k];
  }
  float inv = (e > b) ? 1.0f / (float)(e - b) : 0.0f;
  bf16x8 mv;
#pragma unroll
  for (int j = 0; j < 8; ++j) mv[j] = (__bf16)(acc[j] * inv);
  *reinterpret_cast<bf16x8*>(mean_bf + (size_t)node * DIM + t * 8) = mv;
}

// ---------------- M kernel: m = hs + b_self + hp*(hn + b_neigh) ----------------
// LDS = Wself+Wneigh (64 KB) -> 2 blocks/CU, 4 waves/SIMD. Writes m bf16
// C-layout into mean_bf IN PLACE (each wave reads its 16 mean rows into regs
// before writing m to the same rows; waves own disjoint row slices -> race-free).
__global__ __launch_bounds__(512, 4)
void m_kernel(const __bf16* __restrict__ h_bf,
              __bf16* __restrict__ mm_bf,          // mean in, m out (same buffer)
              const int* __restrict__ counts,
              const float* __restrict__ Wself,
              const float* __restrict__ Wneigh,
              const float* __restrict__ b_self,
              const float* __restrict__ b_neigh) {
  __shared__ __align__(16) char smem[65536];
  char* Wl = smem;
  const int tid = threadIdx.x;

  // stage Wself, Wneigh: f32 -> bf16, XOR-swizzled
  for (int c = tid; c < 4096; c += 512) {
    int mi = c >> 11;
    int w = c & 2047;
    int row = w >> 4, col8 = w & 15;
    const float* src = (mi == 0 ? Wself : Wneigh) + row * 128 + col8 * 8;
    float4 v0 = *reinterpret_cast<const float4*>(src);
    float4 v1 = *reinterpret_cast<const float4*>(src + 4);
    bf16x8 b;
    b[0] = (__bf16)v0.x; b[1] = (__bf16)v0.y; b[2] = (__bf16)v0.z; b[3] = (__bf16)v0.w;
    b[4] = (__bf16)v1.x; b[5] = (__bf16)v1.y; b[6] = (__bf16)v1.z; b[7] = (__bf16)v1.w;
    int byte = (row * 256 + col8 * 16) ^ ((row & 7) << 4);
    *reinterpret_cast<bf16x8*>(Wl + mi * 32768 + byte) = b;
  }
  __syncthreads();

  const int lane = tid & 63;
  const int wave = tid >> 6;
  const int col = lane & 15;
  const int kb = (lane >> 4) << 3;
  const int rloc = (lane >> 4) << 2;

  for (int tile = blockIdx.x; tile < NTILES; tile += MG_GRID) {
    const int node0 = tile * 128;

    bf16x8 a_h[4], a_m[4];
    {
      int n_a = node0 + wave * 16 + col;
      if (n_a < N_NODES) {
#pragma unroll
        for (int k0 = 0; k0 < 4; ++k0) {
          int koff = k0 * 32 + kb;
          a_h[k0] = *reinterpret_cast<const bf16x8*>(h_bf + (size_t)n_a * DIM + koff);
          a_m[k0] = *reinterpret_cast<const bf16x8*>(mm_bf + (size_t)n_a * DIM + koff);
        }
      } else {
#pragma unroll
        for (int k0 = 0; k0 < 4; ++k0)
#pragma unroll
          for (int j = 0; j < 8; ++j) { a_h[k0][j] = (__bf16)0.f; a_m[k0][j] = (__bf16)0.f; }
      }
    }

    int4 c4 = *reinterpret_cast<const int4*>(counts + node0 + wave * 16 + rloc);
    float hp[4];
    {
      int nb0 = node0 + wave * 16 + rloc;
      hp[0] = (nb0 + 0 < N_NODES && c4.x > 0) ? 1.f : 0.f;
      hp[1] = (nb0 + 1 < N_NODES && c4.y > 0) ? 1.f : 0.f;
      hp[2] = (nb0 + 2 < N_NODES && c4.z > 0) ? 1.f : 0.f;
      hp[3] = (nb0 + 3 < N_NODES && c4.w > 0) ? 1.f : 0.f;
    }

    f32x4 sacc[8], nacc[8];
#pragma unroll
    for (int i = 0; i < 8; ++i) {
      sacc[i] = (f32x4){0.f, 0.f, 0.f, 0.f};
      nacc[i] = (f32x4){0.f, 0.f, 0.f, 0.f};
    }
#pragma unroll
    for (int k0 = 0; k0 < 4; ++k0) {
      int koff2 = (k0 * 32 + kb) * 2;
#pragma unroll
      for (int nb = 0; nb < 8; ++nb) {
        int row = nb * 16 + col;
        int swz = (row * 256 + koff2) ^ ((row & 7) << 4);
        bf16x8 bs = *reinterpret_cast<const bf16x8*>(Wl + swz);
        bf16x8 bn = *reinterpret_cast<const bf16x8*>(Wl + 32768 + swz);
        sacc[nb] = __builtin_amdgcn_mfma_f32_16x16x32_bf16(a_h[k0], bs, sacc[nb], 0, 0, 0);
        nacc[nb] = __builtin_amdgcn_mfma_f32_16x16x32_bf16(a_m[k0], bn, nacc[nb], 0, 0, 0);
      }
    }

    // combine and write m (bf16, C-layout, 32B-chunk coalescing)
    const int nrow0 = node0 + wave * 16 + rloc;
#pragma unroll
    for (int nb = 0; nb < 8; ++nb) {
      int d = nb * 16 + col;
      float bs = b_self[d], bn = b_neigh[d];
#pragma unroll
      for (int r = 0; r < 4; ++r) {
        float mval = sacc[nb][r] + bs + hp[r] * (nacc[nb][r] + bn);
        int n = nrow0 + r;
        if (n < N_NODES) mm_bf[(size_t)n * DIM + d] = (__bf16)mval;
      }
    }
  }
}

// ---------------- G kernel: gate GEMMs + blend + LayerNorm + relu ----------------
// LDS = Wgh+Wgm (64 KB) + 8 x 2 KB half-strips = 80 KB -> 2 blocks/CU.
// gate transposed C->A in two 64-col halves through the wave-private strip;
// epilogue in A-layout (h, m already in registers; LN = 2 shfl_xor).
__global__ __launch_bounds__(512, 4)
void g_kernel(const __bf16* __restrict__ h_bf,
              const __bf16* __restrict__ m_bf,
              const float* __restrict__ Wgate,
              const float* __restrict__ b_gate,
              const float* __restrict__ ln_g,
              const float* __restrict__ ln_b,
              float* __restrict__ out) {
  __shared__ __align__(16) char smem[81920];
  char* Wl = smem;
  const int tid = threadIdx.x;

  // stage Wgate halves: cols 0-127 -> Wl, cols 128-255 -> Wl+32768
  for (int c = tid; c < 4096; c += 512) {
    int mi = c >> 11;
    int w = c & 2047;
    int row = w >> 4, col8 = w & 15;
    const float* src = Wgate + row * 256 + mi * 128 + col8 * 8;
    float4 v0 = *reinterpret_cast<const float4*>(src);
    float4 v1 = *reinterpret_cast<const float4*>(src + 4);
    bf16x8 b;
    b[0] = (__bf16)v0.x; b[1] = (__bf16)v0.y; b[2] = (__bf16)v0.z; b[3] = (__bf16)v0.w;
    b[4] = (__bf16)v1.x; b[5] = (__bf16)v1.y; b[6] = (__bf16)v1.z; b[7] = (__bf16)v1.w;
    int byte = (row * 256 + col8 * 16) ^ ((row & 7) << 4);
    *reinterpret_cast<bf16x8*>(Wl + mi * 32768 + byte) = b;
  }
  __syncthreads();

  const int lane = tid & 63;
  const int wave = tid >> 6;
  const int col = lane & 15;
  const int kb = (lane >> 4) << 3;
  const int rloc = (lane >> 4) << 2;
  char* St = smem + 65536 + wave * 2048;   // wave-private: 16 rows x 128 B

  for (int tile = blockIdx.x; tile < NTILES; tile += MG_GRID) {
    const int node0 = tile * 128;

    bf16x8 a_h[4], a_m[4];
    {
      int n_a = node0 + wave * 16 + col;
      if (n_a < N_NODES) {
#pragma unroll
        for (int k0 = 0; k0 < 4; ++k0) {
          int koff = k0 * 32 + kb;
          a_h[k0] = *reinterpret_cast<const bf16x8*>(h_bf + (size_t)n_a * DIM + koff);
          a_m[k0] = *reinterpret_cast<const bf16x8*>(m_bf + (size_t)n_a * DIM + koff);
        }
      } else {
#pragma unroll
        for (int k0 = 0; k0 < 4; ++k0)
#pragma unroll
          for (int j = 0; j < 8; ++j) { a_h[k0][j] = (__bf16)0.f; a_m[k0][j] = (__bf16)0.f; }
      }
    }

    f32x4 gacc[8];
#pragma unroll
    for (int i = 0; i < 8; ++i) gacc[i] = (f32x4){0.f, 0.f, 0.f, 0.f};
#pragma unroll
    for (int k0 = 0; k0 < 4; ++k0) {
      int koff2 = (k0 * 32 + kb) * 2;
#pragma unroll
      for (int nb = 0; nb < 8; ++nb) {
        int row = nb * 16 + col;
        int swz = (row * 256 + koff2) ^ ((row & 7) << 4);
        bf16x8 bgh = *reinterpret_cast<const bf16x8*>(Wl + swz);
        bf16x8 bgm = *reinterpret_cast<const bf16x8*>(Wl + 32768 + swz);
        gacc[nb] = __builtin_amdgcn_mfma_f32_16x16x32_bf16(a_h[k0], bgh, gacc[nb], 0, 0, 0);
        gacc[nb] = __builtin_amdgcn_mfma_f32_16x16x32_bf16(a_m[k0], bgm, gacc[nb], 0, 0, 0);
      }
    }

    // transpose gate C->A in two 64-col halves (same-wave DS ops are in-order)
    bf16x8 gt[4];
#pragma unroll
    for (int half = 0; half < 2; ++half) {
#pragma unroll
      for (int nbl = 0; nbl < 4; ++nbl) {
        int nb = half * 4 + nbl;
        int offd = nb * 16 + col - half * 64;   // [0,64)
#pragma unroll
        for (int r = 0; r < 4; ++r) {
          int rl = rloc + r;
          int byte = (rl * 128 + offd * 2) ^ ((rl & 7) << 4);
          *reinterpret_cast<__bf16*>(St + byte) = (__bf16)gacc[nb][r];
        }
      }
#pragma unroll
      for (int kk = 0; kk < 2; ++kk) {
        int k0 = half * 2 + kk;
        int off = k0 * 32 + kb - half * 64;     // [0,64)
        int byte = (col * 128 + off * 2) ^ ((col & 7) << 4);
        gt[k0] = *reinterpret_cast<const bf16x8*>(St + byte);
      }
    }

    // epilogue in A-layout: row = node (col), cols = k0*32+kb+j
    float s1 = 0.f, s2 = 0.f;
    float vv[4][8];
#pragma unroll
    for (int k0 = 0; k0 < 4; ++k0) {
      int c0 = k0 * 32 + kb;
      float4 bg0 = *reinterpret_cast<const float4*>(b_gate + c0);
      float4 bg1 = *reinterpret_cast<const float4*>(b_gate + c0 + 4);
      float bgv[8] = {bg0.x, bg0.y, bg0.z, bg0.w, bg1.x, bg1.y, bg1.z, bg1.w};
#pragma unroll
      for (int j = 0; j < 8; ++j) {
        float g = 1.0f / (1.0f + __expf(-((float)gt[k0][j] + bgv[j])));
        float v = g * (float)a_m[k0][j] + (1.0f - g) * (float)a_h[k0][j];
        vv[k0][j] = v;
        s1 += v;
        s2 += v * v;
      }
    }
    s1 += __shfl_xor(s1, 16); s1 += __shfl_xor(s1, 32);
    s2 += __shfl_xor(s2, 16); s2 += __shfl_xor(s2, 32);
    float mu = s1 * (1.0f / DIM);
    float var = s2 * (1.0f / DIM) - mu * mu;
    float rs = rsqrtf(var + LN_EPS);

    {
      int gn = node0 + wave * 16 + col;
      bool valid = gn < N_NODES;
#pragma unroll
      for (int k0 = 0; k0 < 4; ++k0) {
        int c0 = k0 * 32 + kb;
        float4 g0 = *reinterpret_cast<const float4*>(ln_g + c0);
        float4 g1 = *reinterpret_cast<const float4*>(ln_g + c0 + 4);
        float4 e0 = *reinterpret_cast<const float4*>(ln_b + c0);
        float4 e1 = *reinterpret_cast<const float4*>(ln_b + c0 + 4);
        float4 o0, o1;
        o0.x = fmaxf((vv[k0][0] - mu) * rs * g0.x + e0.x, 0.f);
        o0.y = fmaxf((vv[k0][1] - mu) * rs * g0.y + e0.y, 0.f);
        o0.z = fmaxf((vv[k0][2] - mu) * rs * g0.z + e0.z, 0.f);
        o0.w = fmaxf((vv[k0][3] - mu) * rs * g0.w + e0.w, 0.f);
        o1.x = fmaxf((vv[k0][4] - mu) * rs * g1.x + e1.x, 0.f);
        o1.y = fmaxf((vv[k0][5] - mu) * rs * g1.y + e1.y, 0.f);
        o1.z = fmaxf((vv[k0][6] - mu) * rs * g1.z + e1.z, 0.f);
        o1.w = fmaxf((vv[k0][7] - mu) * rs * g1.w + e1.w, 0.f);
        if (valid) {
          *reinterpret_cast<float4*>(out + (size_t)gn * DIM + c0) = o0;
          *reinterpret_cast<float4*>(out + (size_t)gn * DIM + c0 + 4) = o1;
        }
      }
    }
  }
}

extern "C" void kernel_launch(void* const* d_in, const int* in_sizes, int n_in,
                              void* d_out, int out_size, void* d_ws, size_t ws_size,
                              hipStream_t stream) {
  const float* h      = (const float*)d_in[0];
  const int*   esrc   = (const int*)d_in[1];
  const int*   edst   = (const int*)d_in[2];
  const float* Wself  = (const float*)d_in[3];
  const float* bself  = (const float*)d_in[4];
  const float* Wneigh = (const float*)d_in[5];
  const float* bneigh = (const float*)d_in[6];
  const float* Wgate  = (const float*)d_in[7];
  const float* bgate  = (const float*)d_in[8];
  const float* ln_g   = (const float*)d_in[9];
  const float* ln_b   = (const float*)d_in[10];
  float* out = (float*)d_out;

  char* ws = (char*)d_ws;
  int* counts   = (int*)ws;                      // 400,000 B
  int* row_off  = (int*)(ws + 400384);           // 400,004 B
  int* cursor   = (int*)(ws + 800768);           // 400,000 B
  int* csr_src  = (int*)(ws + 1200768);          // 2,400,000 B
  int* blk_sums = (int*)(ws + 3600768);          // 1,564 B
  __bf16* h_bf    = (__bf16*)(ws + 3602432);     // 25,600,000 B
  __bf16* mm_bf   = (__bf16*)(ws + 29202432);    // 25,600,000 B (mean, then m in place)

  hipMemsetAsync(counts, 0, (size_t)N_NODES * sizeof(int), stream);

  prep_kernel<<<6250, 256, 0, stream>>>(h, edst, h_bf, counts);
  scan1_kernel<<<SCAN_NBLK, 256, 0, stream>>>(counts, blk_sums);
  scan3_kernel<<<SCAN_NBLK, 256, 0, stream>>>(counts, blk_sums, row_off, cursor);
  csr_fill_kernel<<<(N_EDGES / 4 + 255) / 256, 256, 0, stream>>>(esrc, edst, row_off, cursor, csr_src);
  gather_kernel<<<(N_NODES + 15) / 16, 256, 0, stream>>>(h_bf, csr_src, row_off, mm_bf);
  m_kernel<<<MG_GRID, 512, 0, stream>>>(h_bf, mm_bf, counts, Wself, Wneigh, bself, bneigh);
  g_kernel<<<MG_GRID, 512, 0, stream>>>(h_bf, mm_bf, Wgate, bgate, ln_g, ln_b, out);
}

// Round 11
// 223.977 us; speedup vs baseline: 1.5782x; 1.5782x over previous
//
#include <hip/hip_runtime.h>
#include <math.h>

#define N_NODES 100000
#define N_EDGES 600000
#define DIM 128
#define LN_EPS 1e-5f
#define SCAN_NBLK ((N_NODES + 255) / 256)  // 391
#define NTILES ((N_NODES + 127) / 128)     // 782
#define MG_GRID 512

typedef __bf16 bf16x8 __attribute__((ext_vector_type(8)));
typedef __bf16 bf16x4 __attribute__((ext_vector_type(4)));
typedef float f32x4 __attribute__((ext_vector_type(4)));

// ---------------- prep: h f32 -> bf16 (8 elems/thread), fused degree count ----------------
__global__ __launch_bounds__(256)
void prep_kernel(const float* __restrict__ h, const int* __restrict__ edst,
                 __bf16* __restrict__ h_bf, int* __restrict__ counts) {
  int i = blockIdx.x * 256 + threadIdx.x;  // 1,600,000 threads exactly
  {
    const float4 v0 = *reinterpret_cast<const float4*>(h + (size_t)i * 8);
    const float4 v1 = *reinterpret_cast<const float4*>(h + (size_t)i * 8 + 4);
    bf16x8 b;
    b[0] = (__bf16)v0.x; b[1] = (__bf16)v0.y; b[2] = (__bf16)v0.z; b[3] = (__bf16)v0.w;
    b[4] = (__bf16)v1.x; b[5] = (__bf16)v1.y; b[6] = (__bf16)v1.z; b[7] = (__bf16)v1.w;
    *reinterpret_cast<bf16x8*>(h_bf + (size_t)i * 8) = b;
  }
  if (i < N_EDGES) atomicAdd(&counts[edst[i]], 1);
}

// ---------------- CSR build ----------------
__global__ __launch_bounds__(256)
void scan1_kernel(const int* __restrict__ counts, int* __restrict__ block_sums) {
  int i = blockIdx.x * 256 + threadIdx.x;
  int v = (i < N_NODES) ? counts[i] : 0;
#pragma unroll
  for (int off = 1; off < 64; off <<= 1) v += __shfl_xor(v, off);
  __shared__ int ws[4];
  if ((threadIdx.x & 63) == 0) ws[threadIdx.x >> 6] = v;
  __syncthreads();
  if (threadIdx.x == 0) block_sums[blockIdx.x] = ws[0] + ws[1] + ws[2] + ws[3];
}

__global__ __launch_bounds__(256)
void scan3_kernel(const int* __restrict__ counts, const int* __restrict__ block_sums,
                  int* __restrict__ row_off, int* __restrict__ cursor) {
  const int i = blockIdx.x * 256 + threadIdx.x;
  const int t = threadIdx.x;
  const int lane = t & 63, wv = t >> 6;
  __shared__ int wtot[4];
  __shared__ int sbase[4];

  int partial = 0;
  for (int j = t; j < blockIdx.x; j += 256) partial += block_sums[j];
#pragma unroll
  for (int off = 1; off < 64; off <<= 1) partial += __shfl_xor(partial, off);
  if (lane == 0) sbase[wv] = partial;
  __syncthreads();
  const int base = sbase[0] + sbase[1] + sbase[2] + sbase[3];

  int v = (i < N_NODES) ? counts[i] : 0;
  int s = v;
#pragma unroll
  for (int off = 1; off < 64; off <<= 1) {
    int u = __shfl_up(s, off);
    if (lane >= off) s += u;
  }
  if (lane == 63) wtot[wv] = s;
  __syncthreads();
  int wo = 0;
  for (int w = 0; w < wv; ++w) wo += wtot[w];
  int excl = base + wo + (s - v);
  if (i < N_NODES) { row_off[i] = excl; cursor[i] = 0; }
  if (i == 0) row_off[N_NODES] = N_EDGES;
}

__global__ __launch_bounds__(256)
void csr_fill_kernel(const int* __restrict__ esrc, const int* __restrict__ edst,
                     const int* __restrict__ row_off, int* __restrict__ cursor,
                     int* __restrict__ csr_src) {
  int base = (blockIdx.x * 256 + threadIdx.x) * 4;
  if (base >= N_EDGES) return;
  int4 s4 = *reinterpret_cast<const int4*>(esrc + base);
  int4 d4 = *reinterpret_cast<const int4*>(edst + base);
  {
    int pos = atomicAdd(&cursor[d4.x], 1);
    csr_src[row_off[d4.x] + pos] = s4.x;
  }
  {
    int pos = atomicAdd(&cursor[d4.y], 1);
    csr_src[row_off[d4.y] + pos] = s4.y;
  }
  {
    int pos = atomicAdd(&cursor[d4.z], 1);
    csr_src[row_off[d4.z] + pos] = s4.z;
  }
  {
    int pos = atomicAdd(&cursor[d4.w], 1);
    csr_src[row_off[d4.w] + pos] = s4.w;
  }
}

// ---------------- gather mean: 16 lanes x 16B per node, batch-8 rows in flight ----------------
__global__ __launch_bounds__(256)
void gather_kernel(const __bf16* __restrict__ h_bf, const int* __restrict__ csr_src,
                   const int* __restrict__ row_off, __bf16* __restrict__ mean_bf) {
  int node = blockIdx.x * 16 + (threadIdx.x >> 4);
  if (node >= N_NODES) return;
  int t = threadIdx.x & 15;
  int b = row_off[node], e = row_off[node + 1];
  float acc[8];
#pragma unroll
  for (int j = 0; j < 8; ++j) acc[j] = 0.f;
  for (int i = b; i < e; i += 8) {
    int idx[8];
#pragma unroll
    for (int j = 0; j < 8; ++j) idx[j] = (i + j < e) ? csr_src[i + j] : -1;
    bf16x8 v[8];
#pragma unroll
    for (int j = 0; j < 8; ++j) {
      if (idx[j] >= 0)
        v[j] = *reinterpret_cast<const bf16x8*>(h_bf + (size_t)idx[j] * DIM + t * 8);
      else
#pragma unroll
        for (int k = 0; k < 8; ++k) v[j][k] = (__bf16)0.f;
    }
#pragma unroll
    for (int j = 0; j < 8; ++j)
#pragma unroll
      for (int k = 0; k < 8; ++k) acc[k] += (float)v[j][k];
  }
  float inv = (e > b) ? 1.0f / (float)(e - b) : 0.0f;
  bf16x8 mv;
#pragma unroll
  for (int j = 0; j < 8; ++j) mv[j] = (__bf16)(acc[j] * inv);
  *reinterpret_cast<bf16x8*>(mean_bf + (size_t)node * DIM + t * 8) = mv;
}

// ---------------- M kernel: m = hs + b_self + hp*(hn + b_neigh) ----------------
// LDS = Wself+Wneigh (64 KB). __launch_bounds__(512,1): empirically this
// toolchain allocates 128 VGPRs (fits; arg>=4 drops the cap to 64 and spills
// catastrophically -- R10). HW occupancy: 64KB LDS + 128 VGPR -> 2 blocks/CU
// = 4 waves/SIMD without any allocator starvation.
__global__ __launch_bounds__(512, 1)
void m_kernel(const __bf16* __restrict__ h_bf,
              __bf16* __restrict__ mm_bf,          // mean in, m out (same buffer)
              const int* __restrict__ counts,
              const float* __restrict__ Wself,
              const float* __restrict__ Wneigh,
              const float* __restrict__ b_self,
              const float* __restrict__ b_neigh) {
  __shared__ __align__(16) char smem[65536];
  char* Wl = smem;
  const int tid = threadIdx.x;

  // stage Wself, Wneigh: f32 -> bf16, XOR-swizzled
  for (int c = tid; c < 4096; c += 512) {
    int mi = c >> 11;
    int w = c & 2047;
    int row = w >> 4, col8 = w & 15;
    const float* src = (mi == 0 ? Wself : Wneigh) + row * 128 + col8 * 8;
    float4 v0 = *reinterpret_cast<const float4*>(src);
    float4 v1 = *reinterpret_cast<const float4*>(src + 4);
    bf16x8 b;
    b[0] = (__bf16)v0.x; b[1] = (__bf16)v0.y; b[2] = (__bf16)v0.z; b[3] = (__bf16)v0.w;
    b[4] = (__bf16)v1.x; b[5] = (__bf16)v1.y; b[6] = (__bf16)v1.z; b[7] = (__bf16)v1.w;
    int byte = (row * 256 + col8 * 16) ^ ((row & 7) << 4);
    *reinterpret_cast<bf16x8*>(Wl + mi * 32768 + byte) = b;
  }
  __syncthreads();

  const int lane = tid & 63;
  const int wave = tid >> 6;
  const int col = lane & 15;
  const int kb = (lane >> 4) << 3;
  const int rloc = (lane >> 4) << 2;

  for (int tile = blockIdx.x; tile < NTILES; tile += MG_GRID) {
    const int node0 = tile * 128;

    bf16x8 a_h[4], a_m[4];
    {
      int n_a = node0 + wave * 16 + col;
      if (n_a < N_NODES) {
#pragma unroll
        for (int k0 = 0; k0 < 4; ++k0) {
          int koff = k0 * 32 + kb;
          a_h[k0] = *reinterpret_cast<const bf16x8*>(h_bf + (size_t)n_a * DIM + koff);
          a_m[k0] = *reinterpret_cast<const bf16x8*>(mm_bf + (size_t)n_a * DIM + koff);
        }
      } else {
#pragma unroll
        for (int k0 = 0; k0 < 4; ++k0)
#pragma unroll
          for (int j = 0; j < 8; ++j) { a_h[k0][j] = (__bf16)0.f; a_m[k0][j] = (__bf16)0.f; }
      }
    }

    int4 c4 = *reinterpret_cast<const int4*>(counts + node0 + wave * 16 + rloc);
    float hp[4];
    {
      int nb0 = node0 + wave * 16 + rloc;
      hp[0] = (nb0 + 0 < N_NODES && c4.x > 0) ? 1.f : 0.f;
      hp[1] = (nb0 + 1 < N_NODES && c4.y > 0) ? 1.f : 0.f;
      hp[2] = (nb0 + 2 < N_NODES && c4.z > 0) ? 1.f : 0.f;
      hp[3] = (nb0 + 3 < N_NODES && c4.w > 0) ? 1.f : 0.f;
    }

    f32x4 sacc[8], nacc[8];
#pragma unroll
    for (int i = 0; i < 8; ++i) {
      sacc[i] = (f32x4){0.f, 0.f, 0.f, 0.f};
      nacc[i] = (f32x4){0.f, 0.f, 0.f, 0.f};
    }
#pragma unroll
    for (int k0 = 0; k0 < 4; ++k0) {
      int koff2 = (k0 * 32 + kb) * 2;
#pragma unroll
      for (int nb = 0; nb < 8; ++nb) {
        int row = nb * 16 + col;
        int swz = (row * 256 + koff2) ^ ((row & 7) << 4);
        bf16x8 bs = *reinterpret_cast<const bf16x8*>(Wl + swz);
        bf16x8 bn = *reinterpret_cast<const bf16x8*>(Wl + 32768 + swz);
        sacc[nb] = __builtin_amdgcn_mfma_f32_16x16x32_bf16(a_h[k0], bs, sacc[nb], 0, 0, 0);
        nacc[nb] = __builtin_amdgcn_mfma_f32_16x16x32_bf16(a_m[k0], bn, nacc[nb], 0, 0, 0);
      }
    }

    // combine and write m (bf16, C-layout)
    const int nrow0 = node0 + wave * 16 + rloc;
#pragma unroll
    for (int nb = 0; nb < 8; ++nb) {
      int d = nb * 16 + col;
      float bs = b_self[d], bn = b_neigh[d];
#pragma unroll
      for (int r = 0; r < 4; ++r) {
        float mval = sacc[nb][r] + bs + hp[r] * (nacc[nb][r] + bn);
        int n = nrow0 + r;
        if (n < N_NODES) mm_bf[(size_t)n * DIM + d] = (__bf16)mval;
      }
    }
  }
}

// ---------------- G kernel: gate GEMMs + blend + LayerNorm + relu ----------------
// LDS = Wgh+Wgm (64 KB) + 8 x 2 KB half-strips = 80 KB -> 2 blocks/CU at 128 VGPR.
__global__ __launch_bounds__(512, 1)
void g_kernel(const __bf16* __restrict__ h_bf,
              const __bf16* __restrict__ m_bf,
              const float* __restrict__ Wgate,
              const float* __restrict__ b_gate,
              const float* __restrict__ ln_g,
              const float* __restrict__ ln_b,
              float* __restrict__ out) {
  __shared__ __align__(16) char smem[81920];
  char* Wl = smem;
  const int tid = threadIdx.x;

  // stage Wgate halves: cols 0-127 -> Wl, cols 128-255 -> Wl+32768
  for (int c = tid; c < 4096; c += 512) {
    int mi = c >> 11;
    int w = c & 2047;
    int row = w >> 4, col8 = w & 15;
    const float* src = Wgate + row * 256 + mi * 128 + col8 * 8;
    float4 v0 = *reinterpret_cast<const float4*>(src);
    float4 v1 = *reinterpret_cast<const float4*>(src + 4);
    bf16x8 b;
    b[0] = (__bf16)v0.x; b[1] = (__bf16)v0.y; b[2] = (__bf16)v0.z; b[3] = (__bf16)v0.w;
    b[4] = (__bf16)v1.x; b[5] = (__bf16)v1.y; b[6] = (__bf16)v1.z; b[7] = (__bf16)v1.w;
    int byte = (row * 256 + col8 * 16) ^ ((row & 7) << 4);
    *reinterpret_cast<bf16x8*>(Wl + mi * 32768 + byte) = b;
  }
  __syncthreads();

  const int lane = tid & 63;
  const int wave = tid >> 6;
  const int col = lane & 15;
  const int kb = (lane >> 4) << 3;
  const int rloc = (lane >> 4) << 2;
  char* St = smem + 65536 + wave * 2048;   // wave-private: 16 rows x 128 B

  for (int tile = blockIdx.x; tile < NTILES; tile += MG_GRID) {
    const int node0 = tile * 128;

    bf16x8 a_h[4], a_m[4];
    {
      int n_a = node0 + wave * 16 + col;
      if (n_a < N_NODES) {
#pragma unroll
        for (int k0 = 0; k0 < 4; ++k0) {
          int koff = k0 * 32 + kb;
          a_h[k0] = *reinterpret_cast<const bf16x8*>(h_bf + (size_t)n_a * DIM + koff);
          a_m[k0] = *reinterpret_cast<const bf16x8*>(m_bf + (size_t)n_a * DIM + koff);
        }
      } else {
#pragma unroll
        for (int k0 = 0; k0 < 4; ++k0)
#pragma unroll
          for (int j = 0; j < 8; ++j) { a_h[k0][j] = (__bf16)0.f; a_m[k0][j] = (__bf16)0.f; }
      }
    }

    f32x4 gacc[8];
#pragma unroll
    for (int i = 0; i < 8; ++i) gacc[i] = (f32x4){0.f, 0.f, 0.f, 0.f};
#pragma unroll
    for (int k0 = 0; k0 < 4; ++k0) {
      int koff2 = (k0 * 32 + kb) * 2;
#pragma unroll
      for (int nb = 0; nb < 8; ++nb) {
        int row = nb * 16 + col;
        int swz = (row * 256 + koff2) ^ ((row & 7) << 4);
        bf16x8 bgh = *reinterpret_cast<const bf16x8*>(Wl + swz);
        bf16x8 bgm = *reinterpret_cast<const bf16x8*>(Wl + 32768 + swz);
        gacc[nb] = __builtin_amdgcn_mfma_f32_16x16x32_bf16(a_h[k0], bgh, gacc[nb], 0, 0, 0);
        gacc[nb] = __builtin_amdgcn_mfma_f32_16x16x32_bf16(a_m[k0], bgm, gacc[nb], 0, 0, 0);
      }
    }

    // transpose gate C->A in two 64-col halves (same-wave DS ops are in-order)
    bf16x8 gt[4];
#pragma unroll
    for (int half = 0; half < 2; ++half) {
#pragma unroll
      for (int nbl = 0; nbl < 4; ++nbl) {
        int nb = half * 4 + nbl;
        int offd = nb * 16 + col - half * 64;   // [0,64)
#pragma unroll
        for (int r = 0; r < 4; ++r) {
          int rl = rloc + r;
          int byte = (rl * 128 + offd * 2) ^ ((rl & 7) << 4);
          *reinterpret_cast<__bf16*>(St + byte) = (__bf16)gacc[nb][r];
        }
      }
#pragma unroll
      for (int kk = 0; kk < 2; ++kk) {
        int k0 = half * 2 + kk;
        int off = k0 * 32 + kb - half * 64;     // [0,64)
        int byte = (col * 128 + off * 2) ^ ((col & 7) << 4);
        gt[k0] = *reinterpret_cast<const bf16x8*>(St + byte);
      }
    }

    // epilogue in A-layout: row = node (col), cols = k0*32+kb+j
    float s1 = 0.f, s2 = 0.f;
    float vv[4][8];
#pragma unroll
    for (int k0 = 0; k0 < 4; ++k0) {
      int c0 = k0 * 32 + kb;
      float4 bg0 = *reinterpret_cast<const float4*>(b_gate + c0);
      float4 bg1 = *reinterpret_cast<const float4*>(b_gate + c0 + 4);
      float bgv[8] = {bg0.x, bg0.y, bg0.z, bg0.w, bg1.x, bg1.y, bg1.z, bg1.w};
#pragma unroll
      for (int j = 0; j < 8; ++j) {
        float g = 1.0f / (1.0f + __expf(-((float)gt[k0][j] + bgv[j])));
        float v = g * (float)a_m[k0][j] + (1.0f - g) * (float)a_h[k0][j];
        vv[k0][j] = v;
        s1 += v;
        s2 += v * v;
      }
    }
    s1 += __shfl_xor(s1, 16); s1 += __shfl_xor(s1, 32);
    s2 += __shfl_xor(s2, 16); s2 += __shfl_xor(s2, 32);
    float mu = s1 * (1.0f / DIM);
    float var = s2 * (1.0f / DIM) - mu * mu;
    float rs = rsqrtf(var + LN_EPS);

    {
      int gn = node0 + wave * 16 + col;
      bool valid = gn < N_NODES;
#pragma unroll
      for (int k0 = 0; k0 < 4; ++k0) {
        int c0 = k0 * 32 + kb;
        float4 g0 = *reinterpret_cast<const float4*>(ln_g + c0);
        float4 g1 = *reinterpret_cast<const float4*>(ln_g + c0 + 4);
        float4 e0 = *reinterpret_cast<const float4*>(ln_b + c0);
        float4 e1 = *reinterpret_cast<const float4*>(ln_b + c0 + 4);
        float4 o0, o1;
        o0.x = fmaxf((vv[k0][0] - mu) * rs * g0.x + e0.x, 0.f);
        o0.y = fmaxf((vv[k0][1] - mu) * rs * g0.y + e0.y, 0.f);
        o0.z = fmaxf((vv[k0][2] - mu) * rs * g0.z + e0.z, 0.f);
        o0.w = fmaxf((vv[k0][3] - mu) * rs * g0.w + e0.w, 0.f);
        o1.x = fmaxf((vv[k0][4] - mu) * rs * g1.x + e1.x, 0.f);
        o1.y = fmaxf((vv[k0][5] - mu) * rs * g1.y + e1.y, 0.f);
        o1.z = fmaxf((vv[k0][6] - mu) * rs * g1.z + e1.z, 0.f);
        o1.w = fmaxf((vv[k0][7] - mu) * rs * g1.w + e1.w, 0.f);
        if (valid) {
          *reinterpret_cast<float4*>(out + (size_t)gn * DIM + c0) = o0;
          *reinterpret_cast<float4*>(out + (size_t)gn * DIM + c0 + 4) = o1;
        }
      }
    }
  }
}

extern "C" void kernel_launch(void* const* d_in, const int* in_sizes, int n_in,
                              void* d_out, int out_size, void* d_ws, size_t ws_size,
                              hipStream_t stream) {
  const float* h      = (const float*)d_in[0];
  const int*   esrc   = (const int*)d_in[1];
  const int*   edst   = (const int*)d_in[2];
  const float* Wself  = (const float*)d_in[3];
  const float* bself  = (const float*)d_in[4];
  const float* Wneigh = (const float*)d_in[5];
  const float* bneigh = (const float*)d_in[6];
  const float* Wgate  = (const float*)d_in[7];
  const float* bgate  = (const float*)d_in[8];
  const float* ln_g   = (const float*)d_in[9];
  const float* ln_b   = (const float*)d_in[10];
  float* out = (float*)d_out;

  char* ws = (char*)d_ws;
  int* counts   = (int*)ws;                      // 400,000 B
  int* row_off  = (int*)(ws + 400384);           // 400,004 B
  int* cursor   = (int*)(ws + 800768);           // 400,000 B
  int* csr_src  = (int*)(ws + 1200768);          // 2,400,000 B
  int* blk_sums = (int*)(ws + 3600768);          // 1,564 B
  __bf16* h_bf    = (__bf16*)(ws + 3602432);     // 25,600,000 B
  __bf16* mm_bf   = (__bf16*)(ws + 29202432);    // 25,600,000 B (mean, then m in place)

  hipMemsetAsync(counts, 0, (size_t)N_NODES * sizeof(int), stream);

  prep_kernel<<<6250, 256, 0, stream>>>(h, edst, h_bf, counts);
  scan1_kernel<<<SCAN_NBLK, 256, 0, stream>>>(counts, blk_sums);
  scan3_kernel<<<SCAN_NBLK, 256, 0, stream>>>(counts, blk_sums, row_off, cursor);
  csr_fill_kernel<<<(N_EDGES / 4 + 255) / 256, 256, 0, stream>>>(esrc, edst, row_off, cursor, csr_src);
  gather_kernel<<<(N_NODES + 15) / 16, 256, 0, stream>>>(h_bf, csr_src, row_off, mm_bf);
  m_kernel<<<MG_GRID, 512, 0, stream>>>(h_bf, mm_bf, counts, Wself, Wneigh, bself, bneigh);
  g_kernel<<<MG_GRID, 512, 0, stream>>>(h_bf, mm_bf, Wgate, bgate, ln_g, ln_b, out);
}

// Round 12
// 167.189 us; speedup vs baseline: 2.1143x; 1.3397x over previous
//
#include <hip/hip_runtime.h>
#include <math.h>

#define N_NODES 100000
#define N_EDGES 600000
#define DIM 128
#define LN_EPS 1e-5f
#define SCAN_NBLK ((N_NODES + 255) / 256)  // 391
#define NTILES ((N_NODES + 127) / 128)     // 782
#define MG_GRID 512

typedef __bf16 bf16x8 __attribute__((ext_vector_type(8)));
typedef __bf16 bf16x4 __attribute__((ext_vector_type(4)));
typedef float f32x4 __attribute__((ext_vector_type(4)));

// ---------------- prep: h f32 -> bf16 (8 elems/thread), fused degree count ----------------
__global__ __launch_bounds__(256)
void prep_kernel(const float* __restrict__ h, const int* __restrict__ edst,
                 __bf16* __restrict__ h_bf, int* __restrict__ counts) {
  int i = blockIdx.x * 256 + threadIdx.x;  // 1,600,000 threads exactly
  {
    const float4 v0 = *reinterpret_cast<const float4*>(h + (size_t)i * 8);
    const float4 v1 = *reinterpret_cast<const float4*>(h + (size_t)i * 8 + 4);
    bf16x8 b;
    b[0] = (__bf16)v0.x; b[1] = (__bf16)v0.y; b[2] = (__bf16)v0.z; b[3] = (__bf16)v0.w;
    b[4] = (__bf16)v1.x; b[5] = (__bf16)v1.y; b[6] = (__bf16)v1.z; b[7] = (__bf16)v1.w;
    *reinterpret_cast<bf16x8*>(h_bf + (size_t)i * 8) = b;
  }
  if (i < N_EDGES) atomicAdd(&counts[edst[i]], 1);
}

// ---------------- CSR build ----------------
__global__ __launch_bounds__(256)
void scan1_kernel(const int* __restrict__ counts, int* __restrict__ block_sums) {
  int i = blockIdx.x * 256 + threadIdx.x;
  int v = (i < N_NODES) ? counts[i] : 0;
#pragma unroll
  for (int off = 1; off < 64; off <<= 1) v += __shfl_xor(v, off);
  __shared__ int ws[4];
  if ((threadIdx.x & 63) == 0) ws[threadIdx.x >> 6] = v;
  __syncthreads();
  if (threadIdx.x == 0) block_sums[blockIdx.x] = ws[0] + ws[1] + ws[2] + ws[3];
}

__global__ __launch_bounds__(256)
void scan3_kernel(const int* __restrict__ counts, const int* __restrict__ block_sums,
                  int* __restrict__ row_off, int* __restrict__ cursor) {
  const int i = blockIdx.x * 256 + threadIdx.x;
  const int t = threadIdx.x;
  const int lane = t & 63, wv = t >> 6;
  __shared__ int wtot[4];
  __shared__ int sbase[4];

  int partial = 0;
  for (int j = t; j < blockIdx.x; j += 256) partial += block_sums[j];
#pragma unroll
  for (int off = 1; off < 64; off <<= 1) partial += __shfl_xor(partial, off);
  if (lane == 0) sbase[wv] = partial;
  __syncthreads();
  const int base = sbase[0] + sbase[1] + sbase[2] + sbase[3];

  int v = (i < N_NODES) ? counts[i] : 0;
  int s = v;
#pragma unroll
  for (int off = 1; off < 64; off <<= 1) {
    int u = __shfl_up(s, off);
    if (lane >= off) s += u;
  }
  if (lane == 63) wtot[wv] = s;
  __syncthreads();
  int wo = 0;
  for (int w = 0; w < wv; ++w) wo += wtot[w];
  int excl = base + wo + (s - v);
  if (i < N_NODES) { row_off[i] = excl; cursor[i] = 0; }
  if (i == 0) row_off[N_NODES] = N_EDGES;
}

__global__ __launch_bounds__(256)
void csr_fill_kernel(const int* __restrict__ esrc, const int* __restrict__ edst,
                     const int* __restrict__ row_off, int* __restrict__ cursor,
                     int* __restrict__ csr_src) {
  int base = (blockIdx.x * 256 + threadIdx.x) * 4;
  if (base >= N_EDGES) return;
  int4 s4 = *reinterpret_cast<const int4*>(esrc + base);
  int4 d4 = *reinterpret_cast<const int4*>(edst + base);
  {
    int pos = atomicAdd(&cursor[d4.x], 1);
    csr_src[row_off[d4.x] + pos] = s4.x;
  }
  {
    int pos = atomicAdd(&cursor[d4.y], 1);
    csr_src[row_off[d4.y] + pos] = s4.y;
  }
  {
    int pos = atomicAdd(&cursor[d4.z], 1);
    csr_src[row_off[d4.z] + pos] = s4.z;
  }
  {
    int pos = atomicAdd(&cursor[d4.w], 1);
    csr_src[row_off[d4.w] + pos] = s4.w;
  }
}

// ---------------- gather mean: 16 lanes x 16B per node, batch-8 rows in flight ----------------
__global__ __launch_bounds__(256)
void gather_kernel(const __bf16* __restrict__ h_bf, const int* __restrict__ csr_src,
                   const int* __restrict__ row_off, __bf16* __restrict__ mean_bf) {
  int node = blockIdx.x * 16 + (threadIdx.x >> 4);
  if (node >= N_NODES) return;
  int t = threadIdx.x & 15;
  int b = row_off[node], e = row_off[node + 1];
  float acc[8];
#pragma unroll
  for (int j = 0; j < 8; ++j) acc[j] = 0.f;
  for (int i = b; i < e; i += 8) {
    int idx[8];
#pragma unroll
    for (int j = 0; j < 8; ++j) idx[j] = (i + j < e) ? csr_src[i + j] : -1;
    bf16x8 v[8];
#pragma unroll
    for (int j = 0; j < 8; ++j) {
      if (idx[j] >= 0)
        v[j] = *reinterpret_cast<const bf16x8*>(h_bf + (size_t)idx[j] * DIM + t * 8);
      else
#pragma unroll
        for (int k = 0; k < 8; ++k) v[j][k] = (__bf16)0.f;
    }
#pragma unroll
    for (int j = 0; j < 8; ++j)
#pragma unroll
      for (int k = 0; k < 8; ++k) acc[k] += (float)v[j][k];
  }
  float inv = (e > b) ? 1.0f / (float)(e - b) : 0.0f;
  bf16x8 mv;
#pragma unroll
  for (int j = 0; j < 8; ++j) mv[j] = (__bf16)(acc[j] * inv);
  *reinterpret_cast<bf16x8*>(mean_bf + (size_t)node * DIM + t * 8) = mv;
}

// ---------------- M kernel: m = hs + b_self + hp*(hn + b_neigh) ----------------
// LDS = Wself+Wneigh (64 KB) + 8 x 2 KB half-strips = 80 KB -> 2 blocks/CU at
// 128 VGPR (empirical: (512,1) -> 128-VGPR cap; arg>=4 -> 64 and catastrophic
// spill, R10). m is transposed C->A through the wave-private strip and stored
// row-major bf16x8 (64B contiguous per row per instruction) -- the R11 scalar
// C-layout store caused ~5x HBM RMW amplification (FETCH 124 / WRITE 154 MB).
__global__ __launch_bounds__(512, 1)
void m_kernel(const __bf16* __restrict__ h_bf,
              __bf16* __restrict__ mm_bf,          // mean in, m out (same buffer)
              const int* __restrict__ counts,
              const float* __restrict__ Wself,
              const float* __restrict__ Wneigh,
              const float* __restrict__ b_self,
              const float* __restrict__ b_neigh) {
  __shared__ __align__(16) char smem[81920];
  char* Wl = smem;
  const int tid = threadIdx.x;

  // stage Wself, Wneigh: f32 -> bf16, XOR-swizzled
  for (int c = tid; c < 4096; c += 512) {
    int mi = c >> 11;
    int w = c & 2047;
    int row = w >> 4, col8 = w & 15;
    const float* src = (mi == 0 ? Wself : Wneigh) + row * 128 + col8 * 8;
    float4 v0 = *reinterpret_cast<const float4*>(src);
    float4 v1 = *reinterpret_cast<const float4*>(src + 4);
    bf16x8 b;
    b[0] = (__bf16)v0.x; b[1] = (__bf16)v0.y; b[2] = (__bf16)v0.z; b[3] = (__bf16)v0.w;
    b[4] = (__bf16)v1.x; b[5] = (__bf16)v1.y; b[6] = (__bf16)v1.z; b[7] = (__bf16)v1.w;
    int byte = (row * 256 + col8 * 16) ^ ((row & 7) << 4);
    *reinterpret_cast<bf16x8*>(Wl + mi * 32768 + byte) = b;
  }
  __syncthreads();

  const int lane = tid & 63;
  const int wave = tid >> 6;
  const int col = lane & 15;
  const int kb = (lane >> 4) << 3;
  const int rloc = (lane >> 4) << 2;
  char* St = smem + 65536 + wave * 2048;   // wave-private: 16 rows x 128 B

  for (int tile = blockIdx.x; tile < NTILES; tile += MG_GRID) {
    const int node0 = tile * 128;

    bf16x8 a_h[4], a_m[4];
    {
      int n_a = node0 + wave * 16 + col;
      if (n_a < N_NODES) {
#pragma unroll
        for (int k0 = 0; k0 < 4; ++k0) {
          int koff = k0 * 32 + kb;
          a_h[k0] = *reinterpret_cast<const bf16x8*>(h_bf + (size_t)n_a * DIM + koff);
          a_m[k0] = *reinterpret_cast<const bf16x8*>(mm_bf + (size_t)n_a * DIM + koff);
        }
      } else {
#pragma unroll
        for (int k0 = 0; k0 < 4; ++k0)
#pragma unroll
          for (int j = 0; j < 8; ++j) { a_h[k0][j] = (__bf16)0.f; a_m[k0][j] = (__bf16)0.f; }
      }
    }

    int4 c4 = *reinterpret_cast<const int4*>(counts + node0 + wave * 16 + rloc);
    float hp[4];
    {
      int nb0 = node0 + wave * 16 + rloc;
      hp[0] = (nb0 + 0 < N_NODES && c4.x > 0) ? 1.f : 0.f;
      hp[1] = (nb0 + 1 < N_NODES && c4.y > 0) ? 1.f : 0.f;
      hp[2] = (nb0 + 2 < N_NODES && c4.z > 0) ? 1.f : 0.f;
      hp[3] = (nb0 + 3 < N_NODES && c4.w > 0) ? 1.f : 0.f;
    }

    f32x4 sacc[8], nacc[8];
#pragma unroll
    for (int i = 0; i < 8; ++i) {
      sacc[i] = (f32x4){0.f, 0.f, 0.f, 0.f};
      nacc[i] = (f32x4){0.f, 0.f, 0.f, 0.f};
    }
#pragma unroll
    for (int k0 = 0; k0 < 4; ++k0) {
      int koff2 = (k0 * 32 + kb) * 2;
#pragma unroll
      for (int nb = 0; nb < 8; ++nb) {
        int row = nb * 16 + col;
        int swz = (row * 256 + koff2) ^ ((row & 7) << 4);
        bf16x8 bs = *reinterpret_cast<const bf16x8*>(Wl + swz);
        bf16x8 bn = *reinterpret_cast<const bf16x8*>(Wl + 32768 + swz);
        sacc[nb] = __builtin_amdgcn_mfma_f32_16x16x32_bf16(a_h[k0], bs, sacc[nb], 0, 0, 0);
        nacc[nb] = __builtin_amdgcn_mfma_f32_16x16x32_bf16(a_m[k0], bn, nacc[nb], 0, 0, 0);
      }
    }

    // combine in C-layout -> half-strip -> A-layout regs (sacc/nacc die here)
    bf16x8 am2[4];
#pragma unroll
    for (int half = 0; half < 2; ++half) {
#pragma unroll
      for (int nbl = 0; nbl < 4; ++nbl) {
        int nb = half * 4 + nbl;
        int d = nb * 16 + col;
        float bs = b_self[d], bn = b_neigh[d];
        int offd = d - half * 64;               // [0,64)
#pragma unroll
        for (int r = 0; r < 4; ++r) {
          float mval = sacc[nb][r] + bs + hp[r] * (nacc[nb][r] + bn);
          int rl = rloc + r;
          int byte = (rl * 128 + offd * 2) ^ ((rl & 7) << 4);
          *reinterpret_cast<__bf16*>(St + byte) = (__bf16)mval;
        }
      }
#pragma unroll
      for (int kk = 0; kk < 2; ++kk) {
        int k0 = half * 2 + kk;
        int off = k0 * 32 + kb - half * 64;     // [0,64)
        int byte = (col * 128 + off * 2) ^ ((col & 7) << 4);
        am2[k0] = *reinterpret_cast<const bf16x8*>(St + byte);
      }
    }

    // coalesced row-major store: 64 contiguous B per row per instruction
    {
      int n_a = node0 + wave * 16 + col;
      if (n_a < N_NODES) {
#pragma unroll
        for (int k0 = 0; k0 < 4; ++k0)
          *reinterpret_cast<bf16x8*>(mm_bf + (size_t)n_a * DIM + k0 * 32 + kb) = am2[k0];
      }
    }
  }
}

// ---------------- G kernel: gate GEMMs + blend + LayerNorm + relu ----------------
// LDS = Wgh+Wgm (64 KB) + 8 x 2 KB half-strips = 80 KB -> 2 blocks/CU at 128 VGPR.
__global__ __launch_bounds__(512, 1)
void g_kernel(const __bf16* __restrict__ h_bf,
              const __bf16* __restrict__ m_bf,
              const float* __restrict__ Wgate,
              const float* __restrict__ b_gate,
              const float* __restrict__ ln_g,
              const float* __restrict__ ln_b,
              float* __restrict__ out) {
  __shared__ __align__(16) char smem[81920];
  char* Wl = smem;
  const int tid = threadIdx.x;

  // stage Wgate halves: cols 0-127 -> Wl, cols 128-255 -> Wl+32768
  for (int c = tid; c < 4096; c += 512) {
    int mi = c >> 11;
    int w = c & 2047;
    int row = w >> 4, col8 = w & 15;
    const float* src = Wgate + row * 256 + mi * 128 + col8 * 8;
    float4 v0 = *reinterpret_cast<const float4*>(src);
    float4 v1 = *reinterpret_cast<const float4*>(src + 4);
    bf16x8 b;
    b[0] = (__bf16)v0.x; b[1] = (__bf16)v0.y; b[2] = (__bf16)v0.z; b[3] = (__bf16)v0.w;
    b[4] = (__bf16)v1.x; b[5] = (__bf16)v1.y; b[6] = (__bf16)v1.z; b[7] = (__bf16)v1.w;
    int byte = (row * 256 + col8 * 16) ^ ((row & 7) << 4);
    *reinterpret_cast<bf16x8*>(Wl + mi * 32768 + byte) = b;
  }
  __syncthreads();

  const int lane = tid & 63;
  const int wave = tid >> 6;
  const int col = lane & 15;
  const int kb = (lane >> 4) << 3;
  const int rloc = (lane >> 4) << 2;
  char* St = smem + 65536 + wave * 2048;   // wave-private: 16 rows x 128 B

  for (int tile = blockIdx.x; tile < NTILES; tile += MG_GRID) {
    const int node0 = tile * 128;

    bf16x8 a_h[4], a_m[4];
    {
      int n_a = node0 + wave * 16 + col;
      if (n_a < N_NODES) {
#pragma unroll
        for (int k0 = 0; k0 < 4; ++k0) {
          int koff = k0 * 32 + kb;
          a_h[k0] = *reinterpret_cast<const bf16x8*>(h_bf + (size_t)n_a * DIM + koff);
          a_m[k0] = *reinterpret_cast<const bf16x8*>(m_bf + (size_t)n_a * DIM + koff);
        }
      } else {
#pragma unroll
        for (int k0 = 0; k0 < 4; ++k0)
#pragma unroll
          for (int j = 0; j < 8; ++j) { a_h[k0][j] = (__bf16)0.f; a_m[k0][j] = (__bf16)0.f; }
      }
    }

    f32x4 gacc[8];
#pragma unroll
    for (int i = 0; i < 8; ++i) gacc[i] = (f32x4){0.f, 0.f, 0.f, 0.f};
#pragma unroll
    for (int k0 = 0; k0 < 4; ++k0) {
      int koff2 = (k0 * 32 + kb) * 2;
#pragma unroll
      for (int nb = 0; nb < 8; ++nb) {
        int row = nb * 16 + col;
        int swz = (row * 256 + koff2) ^ ((row & 7) << 4);
        bf16x8 bgh = *reinterpret_cast<const bf16x8*>(Wl + swz);
        bf16x8 bgm = *reinterpret_cast<const bf16x8*>(Wl + 32768 + swz);
        gacc[nb] = __builtin_amdgcn_mfma_f32_16x16x32_bf16(a_h[k0], bgh, gacc[nb], 0, 0, 0);
        gacc[nb] = __builtin_amdgcn_mfma_f32_16x16x32_bf16(a_m[k0], bgm, gacc[nb], 0, 0, 0);
      }
    }

    // transpose gate C->A in two 64-col halves (same-wave DS ops are in-order)
    bf16x8 gt[4];
#pragma unroll
    for (int half = 0; half < 2; ++half) {
#pragma unroll
      for (int nbl = 0; nbl < 4; ++nbl) {
        int nb = half * 4 + nbl;
        int offd = nb * 16 + col - half * 64;   // [0,64)
#pragma unroll
        for (int r = 0; r < 4; ++r) {
          int rl = rloc + r;
          int byte = (rl * 128 + offd * 2) ^ ((rl & 7) << 4);
          *reinterpret_cast<__bf16*>(St + byte) = (__bf16)gacc[nb][r];
        }
      }
#pragma unroll
      for (int kk = 0; kk < 2; ++kk) {
        int k0 = half * 2 + kk;
        int off = k0 * 32 + kb - half * 64;     // [0,64)
        int byte = (col * 128 + off * 2) ^ ((col & 7) << 4);
        gt[k0] = *reinterpret_cast<const bf16x8*>(St + byte);
      }
    }

    // epilogue in A-layout: row = node (col), cols = k0*32+kb+j
    float s1 = 0.f, s2 = 0.f;
    float vv[4][8];
#pragma unroll
    for (int k0 = 0; k0 < 4; ++k0) {
      int c0 = k0 * 32 + kb;
      float4 bg0 = *reinterpret_cast<const float4*>(b_gate + c0);
      float4 bg1 = *reinterpret_cast<const float4*>(b_gate + c0 + 4);
      float bgv[8] = {bg0.x, bg0.y, bg0.z, bg0.w, bg1.x, bg1.y, bg1.z, bg1.w};
#pragma unroll
      for (int j = 0; j < 8; ++j) {
        float g = 1.0f / (1.0f + __expf(-((float)gt[k0][j] + bgv[j])));
        float v = g * (float)a_m[k0][j] + (1.0f - g) * (float)a_h[k0][j];
        vv[k0][j] = v;
        s1 += v;
        s2 += v * v;
      }
    }
    s1 += __shfl_xor(s1, 16); s1 += __shfl_xor(s1, 32);
    s2 += __shfl_xor(s2, 16); s2 += __shfl_xor(s2, 32);
    float mu = s1 * (1.0f / DIM);
    float var = s2 * (1.0f / DIM) - mu * mu;
    float rs = rsqrtf(var + LN_EPS);

    {
      int gn = node0 + wave * 16 + col;
      bool valid = gn < N_NODES;
#pragma unroll
      for (int k0 = 0; k0 < 4; ++k0) {
        int c0 = k0 * 32 + kb;
        float4 g0 = *reinterpret_cast<const float4*>(ln_g + c0);
        float4 g1 = *reinterpret_cast<const float4*>(ln_g + c0 + 4);
        float4 e0 = *reinterpret_cast<const float4*>(ln_b + c0);
        float4 e1 = *reinterpret_cast<const float4*>(ln_b + c0 + 4);
        float4 o0, o1;
        o0.x = fmaxf((vv[k0][0] - mu) * rs * g0.x + e0.x, 0.f);
        o0.y = fmaxf((vv[k0][1] - mu) * rs * g0.y + e0.y, 0.f);
        o0.z = fmaxf((vv[k0][2] - mu) * rs * g0.z + e0.z, 0.f);
        o0.w = fmaxf((vv[k0][3] - mu) * rs * g0.w + e0.w, 0.f);
        o1.x = fmaxf((vv[k0][4] - mu) * rs * g1.x + e1.x, 0.f);
        o1.y = fmaxf((vv[k0][5] - mu) * rs * g1.y + e1.y, 0.f);
        o1.z = fmaxf((vv[k0][6] - mu) * rs * g1.z + e1.z, 0.f);
        o1.w = fmaxf((vv[k0][7] - mu) * rs * g1.w + e1.w, 0.f);
        if (valid) {
          *reinterpret_cast<float4*>(out + (size_t)gn * DIM + c0) = o0;
          *reinterpret_cast<float4*>(out + (size_t)gn * DIM + c0 + 4) = o1;
        }
      }
    }
  }
}

extern "C" void kernel_launch(void* const* d_in, const int* in_sizes, int n_in,
                              void* d_out, int out_size, void* d_ws, size_t ws_size,
                              hipStream_t stream) {
  const float* h      = (const float*)d_in[0];
  const int*   esrc   = (const int*)d_in[1];
  const int*   edst   = (const int*)d_in[2];
  const float* Wself  = (const float*)d_in[3];
  const float* bself  = (const float*)d_in[4];
  const float* Wneigh = (const float*)d_in[5];
  const float* bneigh = (const float*)d_in[6];
  const float* Wgate  = (const float*)d_in[7];
  const float* bgate  = (const float*)d_in[8];
  const float* ln_g   = (const float*)d_in[9];
  const float* ln_b   = (const float*)d_in[10];
  float* out = (float*)d_out;

  char* ws = (char*)d_ws;
  int* counts   = (int*)ws;                      // 400,000 B
  int* row_off  = (int*)(ws + 400384);           // 400,004 B
  int* cursor   = (int*)(ws + 800768);           // 400,000 B
  int* csr_src  = (int*)(ws + 1200768);          // 2,400,000 B
  int* blk_sums = (int*)(ws + 3600768);          // 1,564 B
  __bf16* h_bf    = (__bf16*)(ws + 3602432);     // 25,600,000 B
  __bf16* mm_bf   = (__bf16*)(ws + 29202432);    // 25,600,000 B (mean, then m in place)

  hipMemsetAsync(counts, 0, (size_t)N_NODES * sizeof(int), stream);

  prep_kernel<<<6250, 256, 0, stream>>>(h, edst, h_bf, counts);
  scan1_kernel<<<SCAN_NBLK, 256, 0, stream>>>(counts, blk_sums);
  scan3_kernel<<<SCAN_NBLK, 256, 0, stream>>>(counts, blk_sums, row_off, cursor);
  csr_fill_kernel<<<(N_EDGES / 4 + 255) / 256, 256, 0, stream>>>(esrc, edst, row_off, cursor, csr_src);
  gather_kernel<<<(N_NODES + 15) / 16, 256, 0, stream>>>(h_bf, csr_src, row_off, mm_bf);
  m_kernel<<<MG_GRID, 512, 0, stream>>>(h_bf, mm_bf, counts, Wself, Wneigh, bself, bneigh);
  g_kernel<<<MG_GRID, 512, 0, stream>>>(h_bf, mm_bf, Wgate, bgate, ln_g, ln_b, out);
}

// Round 13
// 166.340 us; speedup vs baseline: 2.1251x; 1.0051x over previous
//
#include <hip/hip_runtime.h>
#include <math.h>

#define N_NODES 100000
#define N_EDGES 600000
#define DIM 128
#define LN_EPS 1e-5f
#define SCAN_NBLK ((N_NODES + 255) / 256)  // 391
#define NTILES ((N_NODES + 127) / 128)     // 782
#define MG_GRID 512

typedef __bf16 bf16x8 __attribute__((ext_vector_type(8)));
typedef __bf16 bf16x4 __attribute__((ext_vector_type(4)));
typedef float f32x4 __attribute__((ext_vector_type(4)));

// ---------------- prep: h f32 -> bf16 (8 elems/thread), fused degree count ----------------
__global__ __launch_bounds__(256)
void prep_kernel(const float* __restrict__ h, const int* __restrict__ edst,
                 __bf16* __restrict__ h_bf, int* __restrict__ counts) {
  int i = blockIdx.x * 256 + threadIdx.x;  // 1,600,000 threads exactly
  {
    const float4 v0 = *reinterpret_cast<const float4*>(h + (size_t)i * 8);
    const float4 v1 = *reinterpret_cast<const float4*>(h + (size_t)i * 8 + 4);
    bf16x8 b;
    b[0] = (__bf16)v0.x; b[1] = (__bf16)v0.y; b[2] = (__bf16)v0.z; b[3] = (__bf16)v0.w;
    b[4] = (__bf16)v1.x; b[5] = (__bf16)v1.y; b[6] = (__bf16)v1.z; b[7] = (__bf16)v1.w;
    *reinterpret_cast<bf16x8*>(h_bf + (size_t)i * 8) = b;
  }
  if (i < N_EDGES) atomicAdd(&counts[edst[i]], 1);
}

// ---------------- CSR build ----------------
__global__ __launch_bounds__(256)
void scan1_kernel(const int* __restrict__ counts, int* __restrict__ block_sums) {
  int i = blockIdx.x * 256 + threadIdx.x;
  int v = (i < N_NODES) ? counts[i] : 0;
#pragma unroll
  for (int off = 1; off < 64; off <<= 1) v += __shfl_xor(v, off);
  __shared__ int ws[4];
  if ((threadIdx.x & 63) == 0) ws[threadIdx.x >> 6] = v;
  __syncthreads();
  if (threadIdx.x == 0) block_sums[blockIdx.x] = ws[0] + ws[1] + ws[2] + ws[3];
}

__global__ __launch_bounds__(256)
void scan3_kernel(const int* __restrict__ counts, const int* __restrict__ block_sums,
                  int* __restrict__ row_off, int* __restrict__ cursor) {
  const int i = blockIdx.x * 256 + threadIdx.x;
  const int t = threadIdx.x;
  const int lane = t & 63, wv = t >> 6;
  __shared__ int wtot[4];
  __shared__ int sbase[4];

  int partial = 0;
  for (int j = t; j < blockIdx.x; j += 256) partial += block_sums[j];
#pragma unroll
  for (int off = 1; off < 64; off <<= 1) partial += __shfl_xor(partial, off);
  if (lane == 0) sbase[wv] = partial;
  __syncthreads();
  const int base = sbase[0] + sbase[1] + sbase[2] + sbase[3];

  int v = (i < N_NODES) ? counts[i] : 0;
  int s = v;
#pragma unroll
  for (int off = 1; off < 64; off <<= 1) {
    int u = __shfl_up(s, off);
    if (lane >= off) s += u;
  }
  if (lane == 63) wtot[wv] = s;
  __syncthreads();
  int wo = 0;
  for (int w = 0; w < wv; ++w) wo += wtot[w];
  int excl = base + wo + (s - v);
  if (i < N_NODES) { row_off[i] = excl; cursor[i] = 0; }
  if (i == 0) row_off[N_NODES] = N_EDGES;
}

__global__ __launch_bounds__(256)
void csr_fill_kernel(const int* __restrict__ esrc, const int* __restrict__ edst,
                     const int* __restrict__ row_off, int* __restrict__ cursor,
                     int* __restrict__ csr_src) {
  int base = (blockIdx.x * 256 + threadIdx.x) * 4;
  if (base >= N_EDGES) return;
  int4 s4 = *reinterpret_cast<const int4*>(esrc + base);
  int4 d4 = *reinterpret_cast<const int4*>(edst + base);
  {
    int pos = atomicAdd(&cursor[d4.x], 1);
    csr_src[row_off[d4.x] + pos] = s4.x;
  }
  {
    int pos = atomicAdd(&cursor[d4.y], 1);
    csr_src[row_off[d4.y] + pos] = s4.y;
  }
  {
    int pos = atomicAdd(&cursor[d4.z], 1);
    csr_src[row_off[d4.z] + pos] = s4.z;
  }
  {
    int pos = atomicAdd(&cursor[d4.w], 1);
    csr_src[row_off[d4.w] + pos] = s4.w;
  }
}

// ---------------- gather mean: 16 lanes x 16B per node, batch-8 rows in flight ----------------
__global__ __launch_bounds__(256)
void gather_kernel(const __bf16* __restrict__ h_bf, const int* __restrict__ csr_src,
                   const int* __restrict__ row_off, __bf16* __restrict__ mean_bf) {
  int node = blockIdx.x * 16 + (threadIdx.x >> 4);
  if (node >= N_NODES) return;
  int t = threadIdx.x & 15;
  int b = row_off[node], e = row_off[node + 1];
  float acc[8];
#pragma unroll
  for (int j = 0; j < 8; ++j) acc[j] = 0.f;
  for (int i = b; i < e; i += 8) {
    int idx[8];
#pragma unroll
    for (int j = 0; j < 8; ++j) idx[j] = (i + j < e) ? csr_src[i + j] : -1;
    bf16x8 v[8];
#pragma unroll
    for (int j = 0; j < 8; ++j) {
      if (idx[j] >= 0)
        v[j] = *reinterpret_cast<const bf16x8*>(h_bf + (size_t)idx[j] * DIM + t * 8);
      else
#pragma unroll
        for (int k = 0; k < 8; ++k) v[j][k] = (__bf16)0.f;
    }
#pragma unroll
    for (int j = 0; j < 8; ++j)
#pragma unroll
      for (int k = 0; k < 8; ++k) acc[k] += (float)v[j][k];
  }
  float inv = (e > b) ? 1.0f / (float)(e - b) : 0.0f;
  bf16x8 mv;
#pragma unroll
  for (int j = 0; j < 8; ++j) mv[j] = (__bf16)(acc[j] * inv);
  *reinterpret_cast<bf16x8*>(mean_bf + (size_t)node * DIM + t * 8) = mv;
}

// ---------------- M kernel: m = hs + b_self + hp*(hn + b_neigh) ----------------
// LDS = 64 KB weights + 8 x 1 KB quarter-strips = 72 KB -> guaranteed 2 blocks/CU
// (R12's 80 KB was exactly 2x160KB and silently fell to 1 block/CU). C->A
// transpose in four 32-col quarter phases through the 1 KB wave-private strip.
// m stored row-major bf16x8 (64B contiguous -- R11's scalar C-layout store
// caused ~5x HBM RMW amplification).
__global__ __launch_bounds__(512, 1)
void m_kernel(const __bf16* __restrict__ h_bf,
              __bf16* __restrict__ mm_bf,          // mean in, m out (same buffer)
              const int* __restrict__ counts,
              const float* __restrict__ Wself,
              const float* __restrict__ Wneigh,
              const float* __restrict__ b_self,
              const float* __restrict__ b_neigh) {
  __shared__ __align__(16) char smem[73728];
  char* Wl = smem;
  const int tid = threadIdx.x;

  // stage Wself, Wneigh: f32 -> bf16, XOR-swizzled
  for (int c = tid; c < 4096; c += 512) {
    int mi = c >> 11;
    int w = c & 2047;
    int row = w >> 4, col8 = w & 15;
    const float* src = (mi == 0 ? Wself : Wneigh) + row * 128 + col8 * 8;
    float4 v0 = *reinterpret_cast<const float4*>(src);
    float4 v1 = *reinterpret_cast<const float4*>(src + 4);
    bf16x8 b;
    b[0] = (__bf16)v0.x; b[1] = (__bf16)v0.y; b[2] = (__bf16)v0.z; b[3] = (__bf16)v0.w;
    b[4] = (__bf16)v1.x; b[5] = (__bf16)v1.y; b[6] = (__bf16)v1.z; b[7] = (__bf16)v1.w;
    int byte = (row * 256 + col8 * 16) ^ ((row & 7) << 4);
    *reinterpret_cast<bf16x8*>(Wl + mi * 32768 + byte) = b;
  }
  __syncthreads();

  const int lane = tid & 63;
  const int wave = tid >> 6;
  const int col = lane & 15;
  const int kb = (lane >> 4) << 3;
  const int rloc = (lane >> 4) << 2;
  char* St = smem + 65536 + wave * 1024;   // wave-private: 16 rows x 64 B

  // hoist tile-invariant biases (lane covers cols {16nb+col})
  float bsv[8], bnv[8];
#pragma unroll
  for (int nb = 0; nb < 8; ++nb) {
    bsv[nb] = b_self[nb * 16 + col];
    bnv[nb] = b_neigh[nb * 16 + col];
  }

  for (int tile = blockIdx.x; tile < NTILES; tile += MG_GRID) {
    const int node0 = tile * 128;

    bf16x8 a_h[4], a_m[4];
    {
      int n_a = node0 + wave * 16 + col;
      if (n_a < N_NODES) {
#pragma unroll
        for (int k0 = 0; k0 < 4; ++k0) {
          int koff = k0 * 32 + kb;
          a_h[k0] = *reinterpret_cast<const bf16x8*>(h_bf + (size_t)n_a * DIM + koff);
          a_m[k0] = *reinterpret_cast<const bf16x8*>(mm_bf + (size_t)n_a * DIM + koff);
        }
      } else {
#pragma unroll
        for (int k0 = 0; k0 < 4; ++k0)
#pragma unroll
          for (int j = 0; j < 8; ++j) { a_h[k0][j] = (__bf16)0.f; a_m[k0][j] = (__bf16)0.f; }
      }
    }

    int4 c4 = *reinterpret_cast<const int4*>(counts + node0 + wave * 16 + rloc);
    float hp[4];
    {
      int nb0 = node0 + wave * 16 + rloc;
      hp[0] = (nb0 + 0 < N_NODES && c4.x > 0) ? 1.f : 0.f;
      hp[1] = (nb0 + 1 < N_NODES && c4.y > 0) ? 1.f : 0.f;
      hp[2] = (nb0 + 2 < N_NODES && c4.z > 0) ? 1.f : 0.f;
      hp[3] = (nb0 + 3 < N_NODES && c4.w > 0) ? 1.f : 0.f;
    }

    f32x4 sacc[8], nacc[8];
#pragma unroll
    for (int i = 0; i < 8; ++i) {
      sacc[i] = (f32x4){0.f, 0.f, 0.f, 0.f};
      nacc[i] = (f32x4){0.f, 0.f, 0.f, 0.f};
    }
#pragma unroll
    for (int k0 = 0; k0 < 4; ++k0) {
      int koff2 = (k0 * 32 + kb) * 2;
#pragma unroll
      for (int nb = 0; nb < 8; ++nb) {
        int row = nb * 16 + col;
        int swz = (row * 256 + koff2) ^ ((row & 7) << 4);
        bf16x8 bs = *reinterpret_cast<const bf16x8*>(Wl + swz);
        bf16x8 bn = *reinterpret_cast<const bf16x8*>(Wl + 32768 + swz);
        sacc[nb] = __builtin_amdgcn_mfma_f32_16x16x32_bf16(a_h[k0], bs, sacc[nb], 0, 0, 0);
        nacc[nb] = __builtin_amdgcn_mfma_f32_16x16x32_bf16(a_m[k0], bn, nacc[nb], 0, 0, 0);
      }
    }

    // combine in C-layout -> quarter-strip -> A-layout regs
    bf16x8 am2[4];
#pragma unroll
    for (int q = 0; q < 4; ++q) {
#pragma unroll
      for (int nbl = 0; nbl < 2; ++nbl) {
        int nb = q * 2 + nbl;
        int offd = nb * 16 + col - q * 32;      // [0,32)
#pragma unroll
        for (int r = 0; r < 4; ++r) {
          float mval = sacc[nb][r] + bsv[nb] + hp[r] * (nacc[nb][r] + bnv[nb]);
          int rl = rloc + r;
          int byte = (rl * 64 + offd * 2) ^ ((rl & 3) << 4);
          *reinterpret_cast<__bf16*>(St + byte) = (__bf16)mval;
        }
      }
      int byte = (col * 64 + kb * 2) ^ ((col & 3) << 4);
      am2[q] = *reinterpret_cast<const bf16x8*>(St + byte);
    }

    // coalesced row-major store: 64 contiguous B per row per instruction
    {
      int n_a = node0 + wave * 16 + col;
      if (n_a < N_NODES) {
#pragma unroll
        for (int k0 = 0; k0 < 4; ++k0)
          *reinterpret_cast<bf16x8*>(mm_bf + (size_t)n_a * DIM + k0 * 32 + kb) = am2[k0];
      }
    }
  }
}

// ---------------- G kernel: gate GEMMs + blend + LayerNorm + relu ----------------
// LDS = 64 KB weights + 8 x 1 KB quarter-strips = 72 KB -> 2 blocks/CU.
__global__ __launch_bounds__(512, 1)
void g_kernel(const __bf16* __restrict__ h_bf,
              const __bf16* __restrict__ m_bf,
              const float* __restrict__ Wgate,
              const float* __restrict__ b_gate,
              const float* __restrict__ ln_g,
              const float* __restrict__ ln_b,
              float* __restrict__ out) {
  __shared__ __align__(16) char smem[73728];
  char* Wl = smem;
  const int tid = threadIdx.x;

  // stage Wgate halves: cols 0-127 -> Wl, cols 128-255 -> Wl+32768
  for (int c = tid; c < 4096; c += 512) {
    int mi = c >> 11;
    int w = c & 2047;
    int row = w >> 4, col8 = w & 15;
    const float* src = Wgate + row * 256 + mi * 128 + col8 * 8;
    float4 v0 = *reinterpret_cast<const float4*>(src);
    float4 v1 = *reinterpret_cast<const float4*>(src + 4);
    bf16x8 b;
    b[0] = (__bf16)v0.x; b[1] = (__bf16)v0.y; b[2] = (__bf16)v0.z; b[3] = (__bf16)v0.w;
    b[4] = (__bf16)v1.x; b[5] = (__bf16)v1.y; b[6] = (__bf16)v1.z; b[7] = (__bf16)v1.w;
    int byte = (row * 256 + col8 * 16) ^ ((row & 7) << 4);
    *reinterpret_cast<bf16x8*>(Wl + mi * 32768 + byte) = b;
  }
  __syncthreads();

  const int lane = tid & 63;
  const int wave = tid >> 6;
  const int col = lane & 15;
  const int kb = (lane >> 4) << 3;
  const int rloc = (lane >> 4) << 2;
  char* St = smem + 65536 + wave * 1024;   // wave-private: 16 rows x 64 B

  for (int tile = blockIdx.x; tile < NTILES; tile += MG_GRID) {
    const int node0 = tile * 128;

    bf16x8 a_h[4], a_m[4];
    {
      int n_a = node0 + wave * 16 + col;
      if (n_a < N_NODES) {
#pragma unroll
        for (int k0 = 0; k0 < 4; ++k0) {
          int koff = k0 * 32 + kb;
          a_h[k0] = *reinterpret_cast<const bf16x8*>(h_bf + (size_t)n_a * DIM + koff);
          a_m[k0] = *reinterpret_cast<const bf16x8*>(m_bf + (size_t)n_a * DIM + koff);
        }
      } else {
#pragma unroll
        for (int k0 = 0; k0 < 4; ++k0)
#pragma unroll
          for (int j = 0; j < 8; ++j) { a_h[k0][j] = (__bf16)0.f; a_m[k0][j] = (__bf16)0.f; }
      }
    }

    f32x4 gacc[8];
#pragma unroll
    for (int i = 0; i < 8; ++i) gacc[i] = (f32x4){0.f, 0.f, 0.f, 0.f};
#pragma unroll
    for (int k0 = 0; k0 < 4; ++k0) {
      int koff2 = (k0 * 32 + kb) * 2;
#pragma unroll
      for (int nb = 0; nb < 8; ++nb) {
        int row = nb * 16 + col;
        int swz = (row * 256 + koff2) ^ ((row & 7) << 4);
        bf16x8 bgh = *reinterpret_cast<const bf16x8*>(Wl + swz);
        bf16x8 bgm = *reinterpret_cast<const bf16x8*>(Wl + 32768 + swz);
        gacc[nb] = __builtin_amdgcn_mfma_f32_16x16x32_bf16(a_h[k0], bgh, gacc[nb], 0, 0, 0);
        gacc[nb] = __builtin_amdgcn_mfma_f32_16x16x32_bf16(a_m[k0], bgm, gacc[nb], 0, 0, 0);
      }
    }

    // transpose gate C->A in four 32-col quarters (same-wave DS ops in-order)
    bf16x8 gt[4];
#pragma unroll
    for (int q = 0; q < 4; ++q) {
#pragma unroll
      for (int nbl = 0; nbl < 2; ++nbl) {
        int nb = q * 2 + nbl;
        int offd = nb * 16 + col - q * 32;      // [0,32)
#pragma unroll
        for (int r = 0; r < 4; ++r) {
          int rl = rloc + r;
          int byte = (rl * 64 + offd * 2) ^ ((rl & 3) << 4);
          *reinterpret_cast<__bf16*>(St + byte) = (__bf16)gacc[q * 2 + nbl][r];
        }
      }
      int byte = (col * 64 + kb * 2) ^ ((col & 3) << 4);
      gt[q] = *reinterpret_cast<const bf16x8*>(St + byte);
    }

    // epilogue in A-layout: row = node (col), cols = k0*32+kb+j
    float s1 = 0.f, s2 = 0.f;
    float vv[4][8];
#pragma unroll
    for (int k0 = 0; k0 < 4; ++k0) {
      int c0 = k0 * 32 + kb;
      float4 bg0 = *reinterpret_cast<const float4*>(b_gate + c0);
      float4 bg1 = *reinterpret_cast<const float4*>(b_gate + c0 + 4);
      float bgv[8] = {bg0.x, bg0.y, bg0.z, bg0.w, bg1.x, bg1.y, bg1.z, bg1.w};
#pragma unroll
      for (int j = 0; j < 8; ++j) {
        float g = 1.0f / (1.0f + __expf(-((float)gt[k0][j] + bgv[j])));
        float v = g * (float)a_m[k0][j] + (1.0f - g) * (float)a_h[k0][j];
        vv[k0][j] = v;
        s1 += v;
        s2 += v * v;
      }
    }
    s1 += __shfl_xor(s1, 16); s1 += __shfl_xor(s1, 32);
    s2 += __shfl_xor(s2, 16); s2 += __shfl_xor(s2, 32);
    float mu = s1 * (1.0f / DIM);
    float var = s2 * (1.0f / DIM) - mu * mu;
    float rs = rsqrtf(var + LN_EPS);

    {
      int gn = node0 + wave * 16 + col;
      bool valid = gn < N_NODES;
#pragma unroll
      for (int k0 = 0; k0 < 4; ++k0) {
        int c0 = k0 * 32 + kb;
        float4 g0 = *reinterpret_cast<const float4*>(ln_g + c0);
        float4 g1 = *reinterpret_cast<const float4*>(ln_g + c0 + 4);
        float4 e0 = *reinterpret_cast<const float4*>(ln_b + c0);
        float4 e1 = *reinterpret_cast<const float4*>(ln_b + c0 + 4);
        float4 o0, o1;
        o0.x = fmaxf((vv[k0][0] - mu) * rs * g0.x + e0.x, 0.f);
        o0.y = fmaxf((vv[k0][1] - mu) * rs * g0.y + e0.y, 0.f);
        o0.z = fmaxf((vv[k0][2] - mu) * rs * g0.z + e0.z, 0.f);
        o0.w = fmaxf((vv[k0][3] - mu) * rs * g0.w + e0.w, 0.f);
        o1.x = fmaxf((vv[k0][4] - mu) * rs * g1.x + e1.x, 0.f);
        o1.y = fmaxf((vv[k0][5] - mu) * rs * g1.y + e1.y, 0.f);
        o1.z = fmaxf((vv[k0][6] - mu) * rs * g1.z + e1.z, 0.f);
        o1.w = fmaxf((vv[k0][7] - mu) * rs * g1.w + e1.w, 0.f);
        if (valid) {
          *reinterpret_cast<float4*>(out + (size_t)gn * DIM + c0) = o0;
          *reinterpret_cast<float4*>(out + (size_t)gn * DIM + c0 + 4) = o1;
        }
      }
    }
  }
}

extern "C" void kernel_launch(void* const* d_in, const int* in_sizes, int n_in,
                              void* d_out, int out_size, void* d_ws, size_t ws_size,
                              hipStream_t stream) {
  const float* h      = (const float*)d_in[0];
  const int*   esrc   = (const int*)d_in[1];
  const int*   edst   = (const int*)d_in[2];
  const float* Wself  = (const float*)d_in[3];
  const float* bself  = (const float*)d_in[4];
  const float* Wneigh = (const float*)d_in[5];
  const float* bneigh = (const float*)d_in[6];
  const float* Wgate  = (const float*)d_in[7];
  const float* bgate  = (const float*)d_in[8];
  const float* ln_g   = (const float*)d_in[9];
  const float* ln_b   = (const float*)d_in[10];
  float* out = (float*)d_out;

  char* ws = (char*)d_ws;
  int* counts   = (int*)ws;                      // 400,000 B
  int* row_off  = (int*)(ws + 400384);           // 400,004 B
  int* cursor   = (int*)(ws + 800768);           // 400,000 B
  int* csr_src  = (int*)(ws + 1200768);          // 2,400,000 B
  int* blk_sums = (int*)(ws + 3600768);          // 1,564 B
  __bf16* h_bf    = (__bf16*)(ws + 3602432);     // 25,600,000 B
  __bf16* mm_bf   = (__bf16*)(ws + 29202432);    // 25,600,000 B (mean, then m in place)

  hipMemsetAsync(counts, 0, (size_t)N_NODES * sizeof(int), stream);

  prep_kernel<<<6250, 256, 0, stream>>>(h, edst, h_bf, counts);
  scan1_kernel<<<SCAN_NBLK, 256, 0, stream>>>(counts, blk_sums);
  scan3_kernel<<<SCAN_NBLK, 256, 0, stream>>>(counts, blk_sums, row_off, cursor);
  csr_fill_kernel<<<(N_EDGES / 4 + 255) / 256, 256, 0, stream>>>(esrc, edst, row_off, cursor, csr_src);
  gather_kernel<<<(N_NODES + 15) / 16, 256, 0, stream>>>(h_bf, csr_src, row_off, mm_bf);
  m_kernel<<<MG_GRID, 512, 0, stream>>>(h_bf, mm_bf, counts, Wself, Wneigh, bself, bneigh);
  g_kernel<<<MG_GRID, 512, 0, stream>>>(h_bf, mm_bf, Wgate, bgate, ln_g, ln_b, out);
}

// Round 14
// 157.414 us; speedup vs baseline: 2.2456x; 1.0567x over previous
//
#include <hip/hip_runtime.h>
#include <math.h>

#define N_NODES 100000
#define N_EDGES 600000
#define DIM 128
#define LN_EPS 1e-5f
#define SCAN_NBLK ((N_NODES + 255) / 256)  // 391
#define NTILES ((N_NODES + 127) / 128)     // 782
#define NODE_GRID 256

typedef __bf16 bf16x8 __attribute__((ext_vector_type(8)));
typedef __bf16 bf16x4 __attribute__((ext_vector_type(4)));
typedef float f32x4 __attribute__((ext_vector_type(4)));

// ---------------- prep: h f32 -> bf16 (8 elems/thread), fused degree count ----------------
__global__ __launch_bounds__(256)
void prep_kernel(const float* __restrict__ h, const int* __restrict__ edst,
                 __bf16* __restrict__ h_bf, int* __restrict__ counts) {
  int i = blockIdx.x * 256 + threadIdx.x;  // 1,600,000 threads exactly
  {
    const float4 v0 = *reinterpret_cast<const float4*>(h + (size_t)i * 8);
    const float4 v1 = *reinterpret_cast<const float4*>(h + (size_t)i * 8 + 4);
    bf16x8 b;
    b[0] = (__bf16)v0.x; b[1] = (__bf16)v0.y; b[2] = (__bf16)v0.z; b[3] = (__bf16)v0.w;
    b[4] = (__bf16)v1.x; b[5] = (__bf16)v1.y; b[6] = (__bf16)v1.z; b[7] = (__bf16)v1.w;
    *reinterpret_cast<bf16x8*>(h_bf + (size_t)i * 8) = b;
  }
  if (i < N_EDGES) atomicAdd(&counts[edst[i]], 1);
}

// ---------------- CSR build ----------------
__global__ __launch_bounds__(256)
void scan1_kernel(const int* __restrict__ counts, int* __restrict__ block_sums) {
  int i = blockIdx.x * 256 + threadIdx.x;
  int v = (i < N_NODES) ? counts[i] : 0;
#pragma unroll
  for (int off = 1; off < 64; off <<= 1) v += __shfl_xor(v, off);
  __shared__ int ws[4];
  if ((threadIdx.x & 63) == 0) ws[threadIdx.x >> 6] = v;
  __syncthreads();
  if (threadIdx.x == 0) block_sums[blockIdx.x] = ws[0] + ws[1] + ws[2] + ws[3];
}

__global__ __launch_bounds__(256)
void scan3_kernel(const int* __restrict__ counts, const int* __restrict__ block_sums,
                  int* __restrict__ row_off, int* __restrict__ cursor) {
  const int i = blockIdx.x * 256 + threadIdx.x;
  const int t = threadIdx.x;
  const int lane = t & 63, wv = t >> 6;
  __shared__ int wtot[4];
  __shared__ int sbase[4];

  int partial = 0;
  for (int j = t; j < blockIdx.x; j += 256) partial += block_sums[j];
#pragma unroll
  for (int off = 1; off < 64; off <<= 1) partial += __shfl_xor(partial, off);
  if (lane == 0) sbase[wv] = partial;
  __syncthreads();
  const int base = sbase[0] + sbase[1] + sbase[2] + sbase[3];

  int v = (i < N_NODES) ? counts[i] : 0;
  int s = v;
#pragma unroll
  for (int off = 1; off < 64; off <<= 1) {
    int u = __shfl_up(s, off);
    if (lane >= off) s += u;
  }
  if (lane == 63) wtot[wv] = s;
  __syncthreads();
  int wo = 0;
  for (int w = 0; w < wv; ++w) wo += wtot[w];
  int excl = base + wo + (s - v);
  if (i < N_NODES) { row_off[i] = excl; cursor[i] = 0; }
  if (i == 0) row_off[N_NODES] = N_EDGES;
}

__global__ __launch_bounds__(256)
void csr_fill_kernel(const int* __restrict__ esrc, const int* __restrict__ edst,
                     const int* __restrict__ row_off, int* __restrict__ cursor,
                     int* __restrict__ csr_src) {
  int base = (blockIdx.x * 256 + threadIdx.x) * 4;
  if (base >= N_EDGES) return;
  int4 s4 = *reinterpret_cast<const int4*>(esrc + base);
  int4 d4 = *reinterpret_cast<const int4*>(edst + base);
  {
    int pos = atomicAdd(&cursor[d4.x], 1);
    csr_src[row_off[d4.x] + pos] = s4.x;
  }
  {
    int pos = atomicAdd(&cursor[d4.y], 1);
    csr_src[row_off[d4.y] + pos] = s4.y;
  }
  {
    int pos = atomicAdd(&cursor[d4.z], 1);
    csr_src[row_off[d4.z] + pos] = s4.z;
  }
  {
    int pos = atomicAdd(&cursor[d4.w], 1);
    csr_src[row_off[d4.w] + pos] = s4.w;
  }
}

// ---------------- fused node kernel v6: in-register gather + two-pass GEMM ----------------
// R9 monolith (proven 58 us, no spill) + mean gather fused into registers:
// wave w's MFMA A-fragment for mean needs only its own 16 rows x 32 lane-cols,
// so each lane accumulates its 32 columns over the node's predecessors directly
// (macc[4][8] f32, batch-2 preds for ILP) -> mean_bf buffer and gather_kernel
// eliminated (saves 25.6 MB write + 25.6 MB read + 1 launch; gather latency
// overlaps other waves' MFMA on the same CU).
__global__ __launch_bounds__(512, 1)
void node_kernel(const __bf16* __restrict__ h_bf,
                 const int* __restrict__ row_off,
                 const int* __restrict__ csr_src,
                 const int* __restrict__ counts,
                 const float* __restrict__ Wself,
                 const float* __restrict__ Wneigh,
                 const float* __restrict__ Wgate,
                 const float* __restrict__ b_self,
                 const float* __restrict__ b_neigh,
                 const float* __restrict__ b_gate,
                 const float* __restrict__ ln_g,
                 const float* __restrict__ ln_b,
                 float* __restrict__ out) {
  __shared__ __align__(16) char smem[163840];
  char* Wl = smem;                       // 4 x 32768 B bf16 weights, XOR-swizzled

  const int tid = threadIdx.x;

  // ---- stage all 4 weight matrices: f32 global -> bf16 LDS ----
  for (int c = tid; c < 8192; c += 512) {
    int mi = c >> 11;
    int w = c & 2047;
    int row = w >> 4, col8 = w & 15;
    const float* src;
    if (mi == 0)      src = Wself  + row * 128 + col8 * 8;
    else if (mi == 1) src = Wneigh + row * 128 + col8 * 8;
    else if (mi == 2) src = Wgate  + row * 256 + col8 * 8;
    else              src = Wgate  + row * 256 + 128 + col8 * 8;
    float4 v0 = *reinterpret_cast<const float4*>(src);
    float4 v1 = *reinterpret_cast<const float4*>(src + 4);
    bf16x8 b;
    b[0] = (__bf16)v0.x; b[1] = (__bf16)v0.y; b[2] = (__bf16)v0.z; b[3] = (__bf16)v0.w;
    b[4] = (__bf16)v1.x; b[5] = (__bf16)v1.y; b[6] = (__bf16)v1.z; b[7] = (__bf16)v1.w;
    int byte = (row * 256 + col8 * 16) ^ ((row & 7) << 4);
    *reinterpret_cast<bf16x8*>(Wl + mi * 32768 + byte) = b;
  }
  __syncthreads();  // only barrier in the kernel

  const int lane = tid & 63;
  const int wave = tid >> 6;
  const int col = lane & 15;
  const int kb = (lane >> 4) << 3;                 // 0,8,16,24
  const int rloc = (lane >> 4) << 2;               // local acc row base (0,4,8,12)
  char* Ms = smem + 131072 + wave * 4096;          // wave-private strip: 16 rows x 256 B

  for (int tile = blockIdx.x; tile < NTILES; tile += NODE_GRID) {
    const int node0 = tile * 128;
    const int n_a = node0 + wave * 16 + col;
    const bool va = n_a < N_NODES;

    // ---- in-register gather: mean of predecessors, this lane's 32 columns ----
    bf16x8 a_m[4];
    {
      int b = 0, e = 0;
      if (va) { b = row_off[n_a]; e = row_off[n_a + 1]; }
      float m0[8], m1[8], m2[8], m3[8];
#pragma unroll
      for (int j = 0; j < 8; ++j) { m0[j] = 0.f; m1[j] = 0.f; m2[j] = 0.f; m3[j] = 0.f; }
      int i = b;
      for (; i + 2 <= e; i += 2) {
        int s0 = csr_src[i], s1 = csr_src[i + 1];
        const __bf16* r0 = h_bf + (size_t)s0 * DIM + kb;
        const __bf16* r1 = h_bf + (size_t)s1 * DIM + kb;
        bf16x8 u0 = *reinterpret_cast<const bf16x8*>(r0);
        bf16x8 u1 = *reinterpret_cast<const bf16x8*>(r0 + 32);
        bf16x8 u2 = *reinterpret_cast<const bf16x8*>(r0 + 64);
        bf16x8 u3 = *reinterpret_cast<const bf16x8*>(r0 + 96);
        bf16x8 w0 = *reinterpret_cast<const bf16x8*>(r1);
        bf16x8 w1 = *reinterpret_cast<const bf16x8*>(r1 + 32);
        bf16x8 w2 = *reinterpret_cast<const bf16x8*>(r1 + 64);
        bf16x8 w3 = *reinterpret_cast<const bf16x8*>(r1 + 96);
#pragma unroll
        for (int j = 0; j < 8; ++j) {
          m0[j] += (float)u0[j] + (float)w0[j];
          m1[j] += (float)u1[j] + (float)w1[j];
          m2[j] += (float)u2[j] + (float)w2[j];
          m3[j] += (float)u3[j] + (float)w3[j];
        }
      }
      if (i < e) {
        int s0 = csr_src[i];
        const __bf16* r0 = h_bf + (size_t)s0 * DIM + kb;
        bf16x8 u0 = *reinterpret_cast<const bf16x8*>(r0);
        bf16x8 u1 = *reinterpret_cast<const bf16x8*>(r0 + 32);
        bf16x8 u2 = *reinterpret_cast<const bf16x8*>(r0 + 64);
        bf16x8 u3 = *reinterpret_cast<const bf16x8*>(r0 + 96);
#pragma unroll
        for (int j = 0; j < 8; ++j) {
          m0[j] += (float)u0[j];
          m1[j] += (float)u1[j];
          m2[j] += (float)u2[j];
          m3[j] += (float)u3[j];
        }
      }
      float inv = (e > b) ? 1.0f / (float)(e - b) : 0.0f;
#pragma unroll
      for (int j = 0; j < 8; ++j) {
        a_m[0][j] = (__bf16)(m0[j] * inv);
        a_m[1][j] = (__bf16)(m1[j] * inv);
        a_m[2][j] = (__bf16)(m2[j] * inv);
        a_m[3][j] = (__bf16)(m3[j] * inv);
      }
    }

    // ---- A_h fragments (after gather to keep register peak low) ----
    bf16x8 a_h[4];
    if (va) {
#pragma unroll
      for (int k0 = 0; k0 < 4; ++k0)
        a_h[k0] = *reinterpret_cast<const bf16x8*>(h_bf + (size_t)n_a * DIM + k0 * 32 + kb);
    } else {
#pragma unroll
      for (int k0 = 0; k0 < 4; ++k0)
#pragma unroll
        for (int j = 0; j < 8; ++j) a_h[k0][j] = (__bf16)0.f;
    }

    // predecessor flags (single int4 load)
    int4 c4 = *reinterpret_cast<const int4*>(counts + node0 + wave * 16 + rloc);
    float hp[4];
    {
      int nb0 = node0 + wave * 16 + rloc;
      hp[0] = (nb0 + 0 < N_NODES && c4.x > 0) ? 1.f : 0.f;
      hp[1] = (nb0 + 1 < N_NODES && c4.y > 0) ? 1.f : 0.f;
      hp[2] = (nb0 + 2 < N_NODES && c4.z > 0) ? 1.f : 0.f;
      hp[3] = (nb0 + 3 < N_NODES && c4.w > 0) ? 1.f : 0.f;
    }

    // ---- PASS 1: hs = h@Wself^T, hn = mean@Wneigh^T ----
    f32x4 sacc[8], nacc[8];
#pragma unroll
    for (int i = 0; i < 8; ++i) {
      sacc[i] = (f32x4){0.f, 0.f, 0.f, 0.f};
      nacc[i] = (f32x4){0.f, 0.f, 0.f, 0.f};
    }
#pragma unroll
    for (int k0 = 0; k0 < 4; ++k0) {
      int koff2 = (k0 * 32 + kb) * 2;
#pragma unroll
      for (int nb = 0; nb < 8; ++nb) {
        int row = nb * 16 + col;
        int swz = (row * 256 + koff2) ^ ((row & 7) << 4);
        bf16x8 bs = *reinterpret_cast<const bf16x8*>(Wl + swz);
        bf16x8 bn = *reinterpret_cast<const bf16x8*>(Wl + 32768 + swz);
        sacc[nb] = __builtin_amdgcn_mfma_f32_16x16x32_bf16(a_h[k0], bs, sacc[nb], 0, 0, 0);
        nacc[nb] = __builtin_amdgcn_mfma_f32_16x16x32_bf16(a_m[k0], bn, nacc[nb], 0, 0, 0);
      }
    }

    // ---- m = hs + b_self + has_pred*(hn + b_neigh); m -> strip (bf16); nacc dies ----
#pragma unroll
    for (int nb = 0; nb < 8; ++nb) {
      int d = nb * 16 + col;
      float bs = b_self[d], bn = b_neigh[d];
#pragma unroll
      for (int r = 0; r < 4; ++r) {
        float mval = sacc[nb][r] + bs + hp[r] * (nacc[nb][r] + bn);
        sacc[nb][r] = mval;  // sacc now holds m
        int rl = rloc + r;
        int byte = (rl * 256 + d * 2) ^ ((rl & 7) << 4);
        *reinterpret_cast<__bf16*>(Ms + byte) = (__bf16)mval;
      }
    }

    // ---- PASS 2: gate = h@Wgh^T + m@Wgm^T (m via strip, same-wave in-order DS) ----
    f32x4 gacc[8];
#pragma unroll
    for (int i = 0; i < 8; ++i) gacc[i] = (f32x4){0.f, 0.f, 0.f, 0.f};
#pragma unroll
    for (int k0 = 0; k0 < 4; ++k0) {
      int koff2 = (k0 * 32 + kb) * 2;
      int abyte = (col * 256 + koff2) ^ ((col & 7) << 4);
      bf16x8 am2 = *reinterpret_cast<const bf16x8*>(Ms + abyte);
#pragma unroll
      for (int nb = 0; nb < 8; ++nb) {
        int row = nb * 16 + col;
        int swz = (row * 256 + koff2) ^ ((row & 7) << 4);
        bf16x8 bgh = *reinterpret_cast<const bf16x8*>(Wl + 65536 + swz);
        bf16x8 bgm = *reinterpret_cast<const bf16x8*>(Wl + 98304 + swz);
        gacc[nb] = __builtin_amdgcn_mfma_f32_16x16x32_bf16(a_h[k0], bgh, gacc[nb], 0, 0, 0);
        gacc[nb] = __builtin_amdgcn_mfma_f32_16x16x32_bf16(am2, bgm, gacc[nb], 0, 0, 0);
      }
    }

    // ---- h fragments -> strip (overwrites m; same-wave DS ops are in-order) ----
#pragma unroll
    for (int k0 = 0; k0 < 4; ++k0) {
      int byte = (col * 256 + (k0 * 32 + kb) * 2) ^ ((col & 7) << 4);
      *reinterpret_cast<bf16x8*>(Ms + byte) = a_h[k0];
    }

    // ---- epilogue: g, v (h from strip), LN stats; v -> strip in place ----
    float s1[4] = {0.f, 0.f, 0.f, 0.f}, s2[4] = {0.f, 0.f, 0.f, 0.f};
#pragma unroll
    for (int nb = 0; nb < 8; ++nb) {
      int d = nb * 16 + col;
      float bg = b_gate[d];
#pragma unroll
      for (int r = 0; r < 4; ++r) {
        int rl = rloc + r;
        int byte = (rl * 256 + d * 2) ^ ((rl & 7) << 4);
        float hval = (float)*reinterpret_cast<const __bf16*>(Ms + byte);
        float g = 1.0f / (1.0f + __expf(-(gacc[nb][r] + bg)));
        float v = g * sacc[nb][r] + (1.0f - g) * hval;
        s1[r] += v;
        s2[r] += v * v;
        *reinterpret_cast<__bf16*>(Ms + byte) = (__bf16)v;  // element-private slot
      }
    }
#pragma unroll
    for (int off = 1; off < 16; off <<= 1) {
#pragma unroll
      for (int r = 0; r < 4; ++r) {
        s1[r] += __shfl_xor(s1[r], off);
        s2[r] += __shfl_xor(s2[r], off);
      }
    }
    float mu[4], rs[4];
#pragma unroll
    for (int r = 0; r < 4; ++r) {
      mu[r] = s1[r] * (1.0f / DIM);
      float var = s2[r] * (1.0f / DIM) - mu[r] * mu[r];
      rs[r] = rsqrtf(var + LN_EPS);
    }

    // ---- readback v (transposed), LN + relu, vectorized stores ----
    {
      int orow = lane >> 2;                  // local row 0..15
      int ochunk = lane & 3;
      int gn = node0 + wave * 16 + orow;
      int rsel = orow & 3;
      float muv = (rsel & 2) ? ((rsel & 1) ? mu[3] : mu[2]) : ((rsel & 1) ? mu[1] : mu[0]);
      float rsv = (rsel & 2) ? ((rsel & 1) ? rs[3] : rs[2]) : ((rsel & 1) ? rs[1] : rs[0]);
      bool valid = gn < N_NODES;
#pragma unroll
      for (int j = 0; j < 4; ++j) {
        int d0 = ochunk * 8 + j * 32;
        int byte = (orow * 256 + d0 * 2) ^ ((orow & 7) << 4);
        bf16x8 vb = *reinterpret_cast<const bf16x8*>(Ms + byte);
        float4 g0 = *reinterpret_cast<const float4*>(ln_g + d0);
        float4 g1 = *reinterpret_cast<const float4*>(ln_g + d0 + 4);
        float4 e0 = *reinterpret_cast<const float4*>(ln_b + d0);
        float4 e1 = *reinterpret_cast<const float4*>(ln_b + d0 + 4);
        float4 o0, o1;
        o0.x = fmaxf(((float)vb[0] - muv) * rsv * g0.x + e0.x, 0.f);
        o0.y = fmaxf(((float)vb[1] - muv) * rsv * g0.y + e0.y, 0.f);
        o0.z = fmaxf(((float)vb[2] - muv) * rsv * g0.z + e0.z, 0.f);
        o0.w = fmaxf(((float)vb[3] - muv) * rsv * g0.w + e0.w, 0.f);
        o1.x = fmaxf(((float)vb[4] - muv) * rsv * g1.x + e1.x, 0.f);
        o1.y = fmaxf(((float)vb[5] - muv) * rsv * g1.y + e1.y, 0.f);
        o1.z = fmaxf(((float)vb[6] - muv) * rsv * g1.z + e1.z, 0.f);
        o1.w = fmaxf(((float)vb[7] - muv) * rsv * g1.w + e1.w, 0.f);
        if (valid) {
          *reinterpret_cast<float4*>(out + (size_t)gn * DIM + d0) = o0;
          *reinterpret_cast<float4*>(out + (size_t)gn * DIM + d0 + 4) = o1;
        }
      }
    }
  }
}

extern "C" void kernel_launch(void* const* d_in, const int* in_sizes, int n_in,
                              void* d_out, int out_size, void* d_ws, size_t ws_size,
                              hipStream_t stream) {
  const float* h      = (const float*)d_in[0];
  const int*   esrc   = (const int*)d_in[1];
  const int*   edst   = (const int*)d_in[2];
  const float* Wself  = (const float*)d_in[3];
  const float* bself  = (const float*)d_in[4];
  const float* Wneigh = (const float*)d_in[5];
  const float* bneigh = (const float*)d_in[6];
  const float* Wgate  = (const float*)d_in[7];
  const float* bgate  = (const float*)d_in[8];
  const float* ln_g   = (const float*)d_in[9];
  const float* ln_b   = (const float*)d_in[10];
  float* out = (float*)d_out;

  char* ws = (char*)d_ws;
  int* counts   = (int*)ws;                      // 400,000 B
  int* row_off  = (int*)(ws + 400384);           // 400,004 B
  int* cursor   = (int*)(ws + 800768);           // 400,000 B
  int* csr_src  = (int*)(ws + 1200768);          // 2,400,000 B
  int* blk_sums = (int*)(ws + 3600768);          // 1,564 B
  __bf16* h_bf  = (__bf16*)(ws + 3602432);       // 25,600,000 B

  hipMemsetAsync(counts, 0, (size_t)N_NODES * sizeof(int), stream);

  prep_kernel<<<6250, 256, 0, stream>>>(h, edst, h_bf, counts);
  scan1_kernel<<<SCAN_NBLK, 256, 0, stream>>>(counts, blk_sums);
  scan3_kernel<<<SCAN_NBLK, 256, 0, stream>>>(counts, blk_sums, row_off, cursor);
  csr_fill_kernel<<<(N_EDGES / 4 + 255) / 256, 256, 0, stream>>>(esrc, edst, row_off, cursor, csr_src);
  node_kernel<<<NODE_GRID, 512, 0, stream>>>(
      h_bf, row_off, csr_src, counts, Wself, Wneigh, Wgate,
      bself, bneigh, bgate, ln_g, ln_b, out);
}